// Round 1
// baseline (252.990 us; speedup 1.0000x reference)
//
#include <hip/hip_runtime.h>

typedef unsigned short u16;
typedef unsigned int u32;
typedef __attribute__((ext_vector_type(8))) short short8;
typedef __attribute__((ext_vector_type(4))) float f32x4;

#define DEV static __device__ __forceinline__

DEV u16 f2bf(float x) {
  union { float f; u32 u; } v; v.f = x;
  u32 r = v.u + 0x7fffu + ((v.u >> 16) & 1u);
  return (u16)(r >> 16);
}
DEV float bf2f(u16 x) {
  union { u32 u; float f; } v; v.u = ((u32)x) << 16;
  return v.f;
}

DEV void gload_lds16(const void* g, void* l) {
  __builtin_amdgcn_global_load_lds(
      (__attribute__((address_space(1))) u32*)((void*)g),
      (__attribute__((address_space(3))) u32*)l, 16, 0, 0);
}

DEV void mfma_bf16(f32x4& d, short8 a, short8 b) {
  asm("v_mfma_f32_16x16x32_bf16 %0, %1, %2, %0" : "+v"(d) : "v"(a), "v"(b));
}

// ---------------- fp32 -> bf16 cast (x inputs), 8 elems/thread ----------------
__global__ __launch_bounds__(256) void k_conv_x(const float* __restrict__ in, u16* __restrict__ out) {
  int i = blockIdx.x * 256 + threadIdx.x;
  const float4* p = (const float4*)in;
  float4 a = p[i * 2], b = p[i * 2 + 1];
  short8 o;
  o[0] = (short)f2bf(a.x); o[1] = (short)f2bf(a.y); o[2] = (short)f2bf(a.z); o[3] = (short)f2bf(a.w);
  o[4] = (short)f2bf(b.x); o[5] = (short)f2bf(b.y); o[6] = (short)f2bf(b.z); o[7] = (short)f2bf(b.w);
  ((short8*)out)[i] = o;
}

// ---------------- W[k][n] fp32 -> Wt[n][k] bf16, 64x64 tiles ----------------
__global__ __launch_bounds__(256) void k_conv_wt(const float* __restrict__ W, u16* __restrict__ Wt) {
  __shared__ u16 tile[64][65];
  int t = threadIdx.x;
  int k0 = blockIdx.x * 64, n0 = blockIdx.y * 64;
  int rr = t >> 4, cc = (t & 15) * 4;
#pragma unroll
  for (int i = 0; i < 4; ++i) {
    int r = rr + i * 16;
    float4 v = *(const float4*)&W[(size_t)(k0 + r) * 1024 + n0 + cc];
    tile[r][cc + 0] = f2bf(v.x); tile[r][cc + 1] = f2bf(v.y);
    tile[r][cc + 2] = f2bf(v.z); tile[r][cc + 3] = f2bf(v.w);
  }
  __syncthreads();
#pragma unroll
  for (int i = 0; i < 4; ++i) {
    int n = rr + i * 16;
    u16 a0 = tile[cc + 0][n], a1 = tile[cc + 1][n], a2 = tile[cc + 2][n], a3 = tile[cc + 3][n];
    uint2 pk;
    pk.x = (u32)a0 | ((u32)a1 << 16);
    pk.y = (u32)a2 | ((u32)a3 << 16);
    *(uint2*)&Wt[(size_t)(n0 + n) * 1024 + k0 + cc] = pk;
  }
}

// ---------------- GEMM: C[M=4096][N=1024] = A(bf16) @ Wt^T(bf16) + bias ----------------
// MODE 0: write bf16 to (b,h,s,d) head-split layout.  MODE 1: write fp32 row-major.
template <int MODE>
__global__ __launch_bounds__(256) void k_gemm(const u16* __restrict__ A, const u16* __restrict__ Bt,
                                              const float* __restrict__ bias, void* __restrict__ dst) {
  __shared__ __align__(16) char sA[8192];
  __shared__ __align__(16) char sB[8192];
  const int Kd = 1024;
  int tid = threadIdx.x, lane = tid & 63, w = tid >> 6;
  int l15 = lane & 15, lg = lane >> 4;
  int bm = blockIdx.x * 128, bn = blockIdx.y * 128;
  int wm = (w >> 1) * 64, wn = (w & 1) * 64;
  f32x4 acc[4][4];
#pragma unroll
  for (int i = 0; i < 4; ++i)
#pragma unroll
    for (int j = 0; j < 4; ++j) acc[i][j] = (f32x4){0.f, 0.f, 0.f, 0.f};

  for (int kt = 0; kt < 32; ++kt) {
#pragma unroll
    for (int p = 0; p < 2; ++p) {
      int idx = p * 256 + tid;
      int row = idx >> 2, c16 = idx & 3;
      gload_lds16((const char*)(A + (size_t)(bm + row) * Kd + kt * 32) + c16 * 16, sA + p * 4096 + w * 1024);
      gload_lds16((const char*)(Bt + (size_t)(bn + row) * Kd + kt * 32) + c16 * 16, sB + p * 4096 + w * 1024);
    }
    __syncthreads();
    short8 af[4], bf[4];
#pragma unroll
    for (int i = 0; i < 4; ++i) {
      af[i] = *(const short8*)(sA + (wm + i * 16 + l15) * 64 + lg * 16);
      bf[i] = *(const short8*)(sB + (wn + i * 16 + l15) * 64 + lg * 16);
    }
#pragma unroll
    for (int i = 0; i < 4; ++i)
#pragma unroll
      for (int j = 0; j < 4; ++j) mfma_bf16(acc[i][j], af[i], bf[j]);
    __syncthreads();
  }

  float bv[4];
#pragma unroll
  for (int j = 0; j < 4; ++j) bv[j] = bias[bn + wn + j * 16 + l15];
#pragma unroll
  for (int i = 0; i < 4; ++i) {
#pragma unroll
    for (int j = 0; j < 4; ++j) {
#pragma unroll
      for (int r = 0; r < 4; ++r) {
        int m = bm + wm + i * 16 + lg * 4 + r;
        int n = bn + wn + j * 16 + l15;
        float v = acc[i][j][r] + bv[j];
        if (MODE == 0) {
          int bb = m >> 11, s = m & 2047, h = n >> 6, d = n & 63;
          ((u16*)dst)[(((size_t)(bb * 16 + h)) * 2048 + s) * 64 + d] = f2bf(v);
        } else {
          ((float*)dst)[(size_t)m * 1024 + n] = v;
        }
      }
    }
  }
}

// QKV fused over blockIdx.z
__global__ __launch_bounds__(256) void k_gemm_qkv(const u16* __restrict__ Aq, const u16* __restrict__ Ak,
                                                  const u16* __restrict__ Av, const u16* __restrict__ Wq,
                                                  const u16* __restrict__ Wk, const u16* __restrict__ Wv,
                                                  const float* __restrict__ bq, const float* __restrict__ bk,
                                                  const float* __restrict__ bv, u16* __restrict__ Qo,
                                                  u16* __restrict__ Ko, u16* __restrict__ Vo) {
  int z = blockIdx.z;
  const u16* A = (z == 0) ? Aq : (z == 1) ? Ak : Av;
  const u16* Bt = (z == 0) ? Wq : (z == 1) ? Wk : Wv;
  const float* bias = (z == 0) ? bq : (z == 1) ? bk : bv;
  u16* dst = (z == 0) ? Qo : (z == 1) ? Ko : Vo;

  __shared__ __align__(16) char sA[8192];
  __shared__ __align__(16) char sB[8192];
  const int Kd = 1024;
  int tid = threadIdx.x, lane = tid & 63, w = tid >> 6;
  int l15 = lane & 15, lg = lane >> 4;
  int bm = blockIdx.x * 128, bn = blockIdx.y * 128;
  int wm = (w >> 1) * 64, wn = (w & 1) * 64;
  f32x4 acc[4][4];
#pragma unroll
  for (int i = 0; i < 4; ++i)
#pragma unroll
    for (int j = 0; j < 4; ++j) acc[i][j] = (f32x4){0.f, 0.f, 0.f, 0.f};

  for (int kt = 0; kt < 32; ++kt) {
#pragma unroll
    for (int p = 0; p < 2; ++p) {
      int idx = p * 256 + tid;
      int row = idx >> 2, c16 = idx & 3;
      gload_lds16((const char*)(A + (size_t)(bm + row) * Kd + kt * 32) + c16 * 16, sA + p * 4096 + w * 1024);
      gload_lds16((const char*)(Bt + (size_t)(bn + row) * Kd + kt * 32) + c16 * 16, sB + p * 4096 + w * 1024);
    }
    __syncthreads();
    short8 af[4], bf[4];
#pragma unroll
    for (int i = 0; i < 4; ++i) {
      af[i] = *(const short8*)(sA + (wm + i * 16 + l15) * 64 + lg * 16);
      bf[i] = *(const short8*)(sB + (wn + i * 16 + l15) * 64 + lg * 16);
    }
#pragma unroll
    for (int i = 0; i < 4; ++i)
#pragma unroll
      for (int j = 0; j < 4; ++j) mfma_bf16(acc[i][j], af[i], bf[j]);
    __syncthreads();
  }

  float bvv[4];
#pragma unroll
  for (int j = 0; j < 4; ++j) bvv[j] = bias[bn + wn + j * 16 + l15];
#pragma unroll
  for (int i = 0; i < 4; ++i) {
#pragma unroll
    for (int j = 0; j < 4; ++j) {
#pragma unroll
      for (int r = 0; r < 4; ++r) {
        int m = bm + wm + i * 16 + lg * 4 + r;
        int n = bn + wn + j * 16 + l15;
        float v = acc[i][j][r] + bvv[j];
        int bb = m >> 11, s = m & 2047, h = n >> 6, d = n & 63;
        dst[(((size_t)(bb * 16 + h)) * 2048 + s) * 64 + d] = f2bf(v);
      }
    }
  }
}

// ---------------- RoPE in-place on (32,2048,64) bf16, one pair per thread ----------------
__global__ __launch_bounds__(256) void k_rope(u32* __restrict__ buf) {
  int p = blockIdx.x * 256 + threadIdx.x;  // 2M pairs
  u32 u = buf[p];
  float xe = bf2f((u16)(u & 0xffffu));
  float xo = bf2f((u16)(u >> 16));
  int dp = p & 31;
  int s = (p >> 5) & 2047;
  float theta = exp2f((float)dp * (-2.0f / 64.0f) * 13.287712379549449f);  // 10000^(-2i/64)
  float ang = (float)s * theta;
  float sn, cs;
  sincosf(ang, &sn, &cs);
  float re = xe * cs - xo * sn;
  float ro = xe * sn + xo * cs;
  buf[p] = (u32)f2bf(re) | ((u32)f2bf(ro) << 16);
}

// ---------------- causal flash attention ----------------
// grid (S/64, BH); 4 waves/block, 16 q-rows per wave, KVBLK=64
__global__ __launch_bounds__(256) void k_attn(const u16* __restrict__ Q, const u16* __restrict__ K,
                                              const u16* __restrict__ V, u16* __restrict__ ctx) {
  __shared__ __align__(16) char sK[8192];
  __shared__ __align__(16) char sVt[8192];
  __shared__ __align__(16) char sP[8192];
  const float KL2E = 0.18033688011112042f;  // (1/8) * log2(e)
  int tid = threadIdx.x, lane = tid & 63, w = tid >> 6;
  int l15 = lane & 15, lg = lane >> 4;
  int qb = blockIdx.x * 64, bh = blockIdx.y;
  const u16* Qg = Q + (size_t)bh * 2048 * 64;
  const u16* Kg = K + (size_t)bh * 2048 * 64;
  const u16* Vg = V + (size_t)bh * 2048 * 64;
  int qr = qb + w * 16;

  short8 qf[2];
  qf[0] = *(const short8*)(Qg + (size_t)(qr + l15) * 64 + lg * 8);
  qf[1] = *(const short8*)(Qg + (size_t)(qr + l15) * 64 + 32 + lg * 8);

  f32x4 oacc[4];
#pragma unroll
  for (int i = 0; i < 4; ++i) oacc[i] = (f32x4){0.f, 0.f, 0.f, 0.f};
  float mrow[4] = {-3e38f, -3e38f, -3e38f, -3e38f};
  float lrow[4] = {0.f, 0.f, 0.f, 0.f};
  char* sPw = sP + w * 2048;

  for (int kv = 0; kv < qb + 64; kv += 64) {
    // K tile: global_load_lds with pre-swizzled source (swizzle = XOR 16B-unit with row&7)
#pragma unroll
    for (int p = 0; p < 2; ++p) {
      int l16 = p * 256 + tid;
      int row = l16 >> 3, c16s = l16 & 7;
      int c16 = c16s ^ (row & 7);
      gload_lds16((const char*)(Kg + (size_t)(kv + row) * 64) + c16 * 16, sK + p * 4096 + w * 1024);
    }
    // V tile transposed into sVt[d][key], same row-XOR swizzle on d
    {
      int key = tid >> 2, d0 = (tid & 3) * 16;
      const u16* vp = Vg + (size_t)(kv + key) * 64 + d0;
      short8 v0 = *(const short8*)(vp);
      short8 v1 = *(const short8*)(vp + 8);
#pragma unroll
      for (int j = 0; j < 8; ++j) {
        int d = d0 + j;
        *(u16*)(sVt + ((d * 128 + key * 2) ^ ((d & 7) << 4))) = (u16)(unsigned short)v0[j];
        int d2 = d0 + 8 + j;
        *(u16*)(sVt + ((d2 * 128 + key * 2) ^ ((d2 & 7) << 4))) = (u16)(unsigned short)v1[j];
      }
    }
    __syncthreads();

    if (kv <= qr + 15) {  // wave-uniform: skip fully-masked tiles
      f32x4 sf[4];
#pragma unroll
      for (int nt = 0; nt < 4; ++nt) {
        f32x4 c = (f32x4){0.f, 0.f, 0.f, 0.f};
        int key = nt * 16 + l15;
        int swz = (key & 7) << 4;
#pragma unroll
        for (int kk = 0; kk < 2; ++kk) {
          short8 bfr = *(const short8*)(sK + ((key * 128 + kk * 64 + lg * 16) ^ swz));
          mfma_bf16(c, qf[kk], bfr);
        }
        sf[nt] = c;
      }
      // online softmax (raw scores; SCALE folded into exp2 factor)
#pragma unroll
      for (int r = 0; r < 4; ++r) {
        int q = qr + lg * 4 + r;
        float vmax = -3e38f;
#pragma unroll
        for (int nt = 0; nt < 4; ++nt) {
          float s = sf[nt][r];
          if (kv + nt * 16 + l15 > q) s = -1e9f;
          sf[nt][r] = s;
          vmax = fmaxf(vmax, s);
        }
        vmax = fmaxf(vmax, __shfl_xor(vmax, 1));
        vmax = fmaxf(vmax, __shfl_xor(vmax, 2));
        vmax = fmaxf(vmax, __shfl_xor(vmax, 4));
        vmax = fmaxf(vmax, __shfl_xor(vmax, 8));
        float mnew = fmaxf(mrow[r], vmax);
        float alpha = exp2f((mrow[r] - mnew) * KL2E);
        mrow[r] = mnew;
        float psum = 0.f;
#pragma unroll
        for (int nt = 0; nt < 4; ++nt) {
          float pv = exp2f((sf[nt][r] - mnew) * KL2E);
          sf[nt][r] = pv;
          psum += pv;
        }
        psum += __shfl_xor(psum, 1);
        psum += __shfl_xor(psum, 2);
        psum += __shfl_xor(psum, 4);
        psum += __shfl_xor(psum, 8);
        lrow[r] = lrow[r] * alpha + psum;
#pragma unroll
        for (int dt = 0; dt < 4; ++dt) oacc[dt][r] *= alpha;
      }
      // P -> per-wave LDS (bf16, swizzled), then PV
#pragma unroll
      for (int nt = 0; nt < 4; ++nt)
#pragma unroll
        for (int r = 0; r < 4; ++r) {
          int ql = lg * 4 + r, kl = nt * 16 + l15;
          *(u16*)(sPw + ((ql * 128 + kl * 2) ^ ((ql & 7) << 4))) = f2bf(sf[nt][r]);
        }
#pragma unroll
      for (int dt = 0; dt < 4; ++dt) {
        int d = dt * 16 + l15;
        int swzd = (d & 7) << 4;
#pragma unroll
        for (int ks = 0; ks < 2; ++ks) {
          short8 pa = *(const short8*)(sPw + ((l15 * 128 + ks * 64 + lg * 16) ^ ((l15 & 7) << 4)));
          short8 vb = *(const short8*)(sVt + ((d * 128 + ks * 64 + lg * 16) ^ swzd));
          mfma_bf16(oacc[dt], pa, vb);
        }
      }
    }
    __syncthreads();
  }

  int bb = bh >> 4, h = bh & 15;
#pragma unroll
  for (int dt = 0; dt < 4; ++dt) {
    int d = dt * 16 + l15;
#pragma unroll
    for (int r = 0; r < 4; ++r) {
      int q = qr + lg * 4 + r;
      float v = oacc[dt][r] / lrow[r];
      ctx[((size_t)(bb * 2048 + q)) * 1024 + h * 64 + d] = f2bf(v);
    }
  }
}

extern "C" void kernel_launch(void* const* d_in, const int* in_sizes, int n_in,
                              void* d_out, int out_size, void* d_ws, size_t ws_size,
                              hipStream_t stream) {
  (void)in_sizes; (void)n_in; (void)out_size; (void)ws_size;
  const float* xq = (const float*)d_in[0];
  const float* xk = (const float*)d_in[1];
  const float* xv = (const float*)d_in[2];
  const float* Wq = (const float*)d_in[4];
  const float* bq = (const float*)d_in[5];
  const float* Wk = (const float*)d_in[6];
  const float* bk = (const float*)d_in[7];
  const float* Wv = (const float*)d_in[8];
  const float* bv = (const float*)d_in[9];
  const float* Wo = (const float*)d_in[10];
  const float* bo = (const float*)d_in[11];

  char* ws = (char*)d_ws;
  u16* XQ  = (u16*)(ws);                       // 8MB, dead after QKV gemm
  u16* XK  = (u16*)(ws + ((size_t)8 << 20));   // 8MB
  u16* XV  = (u16*)(ws + ((size_t)16 << 20));  // 8MB
  u16* WTQ = (u16*)(ws + ((size_t)24 << 20));  // 2MB
  u16* WTK = (u16*)(ws + ((size_t)26 << 20));
  u16* WTV = (u16*)(ws + ((size_t)28 << 20));
  u16* WTO = (u16*)(ws + ((size_t)30 << 20));
  u16* Qb  = (u16*)(ws + ((size_t)32 << 20));  // 8MB (32,2048,64) bf16
  u16* Kb  = (u16*)(ws + ((size_t)40 << 20));
  u16* Vb  = (u16*)(ws + ((size_t)48 << 20));
  u16* CTX = (u16*)(ws);                       // aliases XQ (dead by then)

  k_conv_x<<<2048, 256, 0, stream>>>(xq, XQ);
  k_conv_x<<<2048, 256, 0, stream>>>(xk, XK);
  k_conv_x<<<2048, 256, 0, stream>>>(xv, XV);
  dim3 wt(16, 16);
  k_conv_wt<<<wt, 256, 0, stream>>>(Wq, WTQ);
  k_conv_wt<<<wt, 256, 0, stream>>>(Wk, WTK);
  k_conv_wt<<<wt, 256, 0, stream>>>(Wv, WTV);
  k_conv_wt<<<wt, 256, 0, stream>>>(Wo, WTO);
  dim3 gq(32, 8, 3);
  k_gemm_qkv<<<gq, 256, 0, stream>>>(XQ, XK, XV, WTQ, WTK, WTV, bq, bk, bv, Qb, Kb, Vb);
  k_rope<<<8192, 256, 0, stream>>>((u32*)Qb);
  k_rope<<<8192, 256, 0, stream>>>((u32*)Kb);
  dim3 ag(32, 32);
  k_attn<<<ag, 256, 0, stream>>>(Qb, Kb, Vb, CTX);
  dim3 gg(32, 8);
  k_gemm<1><<<gg, 256, 0, stream>>>(CTX, WTO, bo, d_out);
}

// Round 2
// 195.398 us; speedup vs baseline: 1.2947x; 1.2947x over previous
//
#include <hip/hip_runtime.h>

typedef unsigned short u16;
typedef unsigned int u32;
typedef __attribute__((ext_vector_type(8))) short short8;
typedef __attribute__((ext_vector_type(4))) float f32x4;

#define DEV static __device__ __forceinline__

DEV u16 f2bf(float x) {
  union { float f; u32 u; } v; v.f = x;
  u32 r = v.u + 0x7fffu + ((v.u >> 16) & 1u);
  return (u16)(r >> 16);
}
DEV float bf2f(u16 x) {
  union { u32 u; float f; } v; v.u = ((u32)x) << 16;
  return v.f;
}

DEV void gload_lds16(const void* g, void* l) {
  __builtin_amdgcn_global_load_lds(
      (__attribute__((address_space(1))) u32*)((void*)g),
      (__attribute__((address_space(3))) u32*)l, 16, 0, 0);
}

DEV void mfma_bf16(f32x4& d, short8 a, short8 b) {
  asm("v_mfma_f32_16x16x32_bf16 %0, %1, %2, %0" : "+v"(d) : "v"(a), "v"(b));
}

// ---------------- fp32 -> bf16 cast (x inputs), 8 elems/thread ----------------
__global__ __launch_bounds__(256) void k_conv_x(const float* __restrict__ in, u16* __restrict__ out) {
  int i = blockIdx.x * 256 + threadIdx.x;
  const float4* p = (const float4*)in;
  float4 a = p[i * 2], b = p[i * 2 + 1];
  short8 o;
  o[0] = (short)f2bf(a.x); o[1] = (short)f2bf(a.y); o[2] = (short)f2bf(a.z); o[3] = (short)f2bf(a.w);
  o[4] = (short)f2bf(b.x); o[5] = (short)f2bf(b.y); o[6] = (short)f2bf(b.z); o[7] = (short)f2bf(b.w);
  ((short8*)out)[i] = o;
}

// ---------------- W[k][n] fp32 -> Wt[n][k] bf16, 64x64 tiles ----------------
__global__ __launch_bounds__(256) void k_conv_wt(const float* __restrict__ W, u16* __restrict__ Wt) {
  __shared__ u16 tile[64][65];
  int t = threadIdx.x;
  int k0 = blockIdx.x * 64, n0 = blockIdx.y * 64;
  int rr = t >> 4, cc = (t & 15) * 4;
#pragma unroll
  for (int i = 0; i < 4; ++i) {
    int r = rr + i * 16;
    float4 v = *(const float4*)&W[(size_t)(k0 + r) * 1024 + n0 + cc];
    tile[r][cc + 0] = f2bf(v.x); tile[r][cc + 1] = f2bf(v.y);
    tile[r][cc + 2] = f2bf(v.z); tile[r][cc + 3] = f2bf(v.w);
  }
  __syncthreads();
#pragma unroll
  for (int i = 0; i < 4; ++i) {
    int n = rr + i * 16;
    u16 a0 = tile[cc + 0][n], a1 = tile[cc + 1][n], a2 = tile[cc + 2][n], a3 = tile[cc + 3][n];
    uint2 pk;
    pk.x = (u32)a0 | ((u32)a1 << 16);
    pk.y = (u32)a2 | ((u32)a3 << 16);
    *(uint2*)&Wt[(size_t)(n0 + n) * 1024 + k0 + cc] = pk;
  }
}

// ---------------- V (b,h,s,d) bf16 -> Vt (b,h,d,s) bf16, 64x64 tiles ----------------
__global__ __launch_bounds__(256) void k_vtrans(const u16* __restrict__ in, u16* __restrict__ out) {
  __shared__ u16 tile[64][65];
  int t = threadIdx.x;
  int s0 = blockIdx.x * 64;
  size_t base = (size_t)blockIdx.y * 131072;
#pragma unroll
  for (int p = 0; p < 2; ++p) {
    int i = p * 256 + t;
    int r = i >> 3, c = i & 7;
    short8 v = *(const short8*)(in + base + (size_t)(s0 + r) * 64 + c * 8);
#pragma unroll
    for (int j = 0; j < 8; ++j) tile[r][c * 8 + j] = (u16)(unsigned short)v[j];
  }
  __syncthreads();
#pragma unroll
  for (int p = 0; p < 2; ++p) {
    int i = p * 256 + t;
    int d = i >> 3, c = i & 7;
    short8 o;
#pragma unroll
    for (int j = 0; j < 8; ++j) o[j] = (short)tile[c * 8 + j][d];
    *(short8*)(out + base + (size_t)d * 2048 + s0 + c * 8) = o;
  }
}

// ---------------- GEMM: C[M=4096][N=1024] = A(bf16) @ Wt^T(bf16) + bias ----------------
template <int MODE>
__global__ __launch_bounds__(256) void k_gemm(const u16* __restrict__ A, const u16* __restrict__ Bt,
                                              const float* __restrict__ bias, void* __restrict__ dst) {
  __shared__ __align__(16) char sA[8192];
  __shared__ __align__(16) char sB[8192];
  const int Kd = 1024;
  int tid = threadIdx.x, lane = tid & 63, w = tid >> 6;
  int l15 = lane & 15, lg = lane >> 4;
  int bm = blockIdx.x * 128, bn = blockIdx.y * 128;
  int wm = (w >> 1) * 64, wn = (w & 1) * 64;
  f32x4 acc[4][4];
#pragma unroll
  for (int i = 0; i < 4; ++i)
#pragma unroll
    for (int j = 0; j < 4; ++j) acc[i][j] = (f32x4){0.f, 0.f, 0.f, 0.f};

  for (int kt = 0; kt < 32; ++kt) {
#pragma unroll
    for (int p = 0; p < 2; ++p) {
      int idx = p * 256 + tid;
      int row = idx >> 2, c16 = idx & 3;
      gload_lds16((const char*)(A + (size_t)(bm + row) * Kd + kt * 32) + c16 * 16, sA + p * 4096 + w * 1024);
      gload_lds16((const char*)(Bt + (size_t)(bn + row) * Kd + kt * 32) + c16 * 16, sB + p * 4096 + w * 1024);
    }
    __syncthreads();
    short8 af[4], bf[4];
#pragma unroll
    for (int i = 0; i < 4; ++i) {
      af[i] = *(const short8*)(sA + (wm + i * 16 + l15) * 64 + lg * 16);
      bf[i] = *(const short8*)(sB + (wn + i * 16 + l15) * 64 + lg * 16);
    }
#pragma unroll
    for (int i = 0; i < 4; ++i)
#pragma unroll
      for (int j = 0; j < 4; ++j) mfma_bf16(acc[i][j], af[i], bf[j]);
    __syncthreads();
  }

  float bv[4];
#pragma unroll
  for (int j = 0; j < 4; ++j) bv[j] = bias[bn + wn + j * 16 + l15];
#pragma unroll
  for (int i = 0; i < 4; ++i) {
#pragma unroll
    for (int j = 0; j < 4; ++j) {
#pragma unroll
      for (int r = 0; r < 4; ++r) {
        int m = bm + wm + i * 16 + lg * 4 + r;
        int n = bn + wn + j * 16 + l15;
        float v = acc[i][j][r] + bv[j];
        if (MODE == 0) {
          int bb = m >> 11, s = m & 2047, h = n >> 6, d = n & 63;
          ((u16*)dst)[(((size_t)(bb * 16 + h)) * 2048 + s) * 64 + d] = f2bf(v);
        } else {
          ((float*)dst)[(size_t)m * 1024 + n] = v;
        }
      }
    }
  }
}

// QKV fused over blockIdx.z
__global__ __launch_bounds__(256) void k_gemm_qkv(const u16* __restrict__ Aq, const u16* __restrict__ Ak,
                                                  const u16* __restrict__ Av, const u16* __restrict__ Wq,
                                                  const u16* __restrict__ Wk, const u16* __restrict__ Wv,
                                                  const float* __restrict__ bq, const float* __restrict__ bk,
                                                  const float* __restrict__ bv, u16* __restrict__ Qo,
                                                  u16* __restrict__ Ko, u16* __restrict__ Vo) {
  int z = blockIdx.z;
  const u16* A = (z == 0) ? Aq : (z == 1) ? Ak : Av;
  const u16* Bt = (z == 0) ? Wq : (z == 1) ? Wk : Wv;
  const float* bias = (z == 0) ? bq : (z == 1) ? bk : bv;
  u16* dst = (z == 0) ? Qo : (z == 1) ? Ko : Vo;

  __shared__ __align__(16) char sA[8192];
  __shared__ __align__(16) char sB[8192];
  const int Kd = 1024;
  int tid = threadIdx.x, lane = tid & 63, w = tid >> 6;
  int l15 = lane & 15, lg = lane >> 4;
  int bm = blockIdx.x * 128, bn = blockIdx.y * 128;
  int wm = (w >> 1) * 64, wn = (w & 1) * 64;
  f32x4 acc[4][4];
#pragma unroll
  for (int i = 0; i < 4; ++i)
#pragma unroll
    for (int j = 0; j < 4; ++j) acc[i][j] = (f32x4){0.f, 0.f, 0.f, 0.f};

  for (int kt = 0; kt < 32; ++kt) {
#pragma unroll
    for (int p = 0; p < 2; ++p) {
      int idx = p * 256 + tid;
      int row = idx >> 2, c16 = idx & 3;
      gload_lds16((const char*)(A + (size_t)(bm + row) * Kd + kt * 32) + c16 * 16, sA + p * 4096 + w * 1024);
      gload_lds16((const char*)(Bt + (size_t)(bn + row) * Kd + kt * 32) + c16 * 16, sB + p * 4096 + w * 1024);
    }
    __syncthreads();
    short8 af[4], bf[4];
#pragma unroll
    for (int i = 0; i < 4; ++i) {
      af[i] = *(const short8*)(sA + (wm + i * 16 + l15) * 64 + lg * 16);
      bf[i] = *(const short8*)(sB + (wn + i * 16 + l15) * 64 + lg * 16);
    }
#pragma unroll
    for (int i = 0; i < 4; ++i)
#pragma unroll
      for (int j = 0; j < 4; ++j) mfma_bf16(acc[i][j], af[i], bf[j]);
    __syncthreads();
  }

  float bvv[4];
#pragma unroll
  for (int j = 0; j < 4; ++j) bvv[j] = bias[bn + wn + j * 16 + l15];
#pragma unroll
  for (int i = 0; i < 4; ++i) {
#pragma unroll
    for (int j = 0; j < 4; ++j) {
#pragma unroll
      for (int r = 0; r < 4; ++r) {
        int m = bm + wm + i * 16 + lg * 4 + r;
        int n = bn + wn + j * 16 + l15;
        float v = acc[i][j][r] + bvv[j];
        int bb = m >> 11, s = m & 2047, h = n >> 6, d = n & 63;
        dst[(((size_t)(bb * 16 + h)) * 2048 + s) * 64 + d] = f2bf(v);
      }
    }
  }
}

// ---------------- RoPE in-place on (32,2048,64) bf16, one pair per thread ----------------
__global__ __launch_bounds__(256) void k_rope(u32* __restrict__ buf) {
  int p = blockIdx.x * 256 + threadIdx.x;  // 2M pairs
  u32 u = buf[p];
  float xe = bf2f((u16)(u & 0xffffu));
  float xo = bf2f((u16)(u >> 16));
  int dp = p & 31;
  int s = (p >> 5) & 2047;
  float theta = exp2f((float)dp * (-2.0f / 64.0f) * 13.287712379549449f);  // 10000^(-2i/64)
  float ang = (float)s * theta;
  float sn, cs;
  sincosf(ang, &sn, &cs);
  float re = xe * cs - xo * sn;
  float ro = xe * sn + xo * cs;
  buf[p] = (u32)f2bf(re) | ((u32)f2bf(ro) << 16);
}

// ---------------- causal flash attention, swapped-QK^T, lane-parallel softmax ----------------
// grid (32 reversed-qb, 32 bh); 4 waves/block, 16 q-rows per wave, KVBLK=64
__global__ __launch_bounds__(256, 4) void k_attn(const u16* __restrict__ Q, const u16* __restrict__ K,
                                                 const u16* __restrict__ Vt, u16* __restrict__ ctx) {
  __shared__ __align__(16) char sK[2][8192];
  __shared__ __align__(16) char sV[2][8192];
  __shared__ __align__(16) char sP[4][2048];
  const float KL2E = 0.18033688011112042f;  // (1/8) * log2(e)
  int tid = threadIdx.x, lane = tid & 63, w = tid >> 6;
  int l15 = lane & 15, lg = lane >> 4;
  int qb = (31 - blockIdx.x) * 64;  // heavy blocks first
  int bh = blockIdx.y;
  const u16* Qg = Q + (size_t)bh * 131072;
  const u16* Kg = K + (size_t)bh * 131072;
  const u16* Vg = Vt + (size_t)bh * 131072;
  int qr = qb + w * 16;
  int qa = qr + l15;  // this lane's q row (score/softmax owner)

  short8 qf[2];
  qf[0] = *(const short8*)(Qg + (size_t)(qr + l15) * 64 + lg * 8);
  qf[1] = *(const short8*)(Qg + (size_t)(qr + l15) * 64 + 32 + lg * 8);

  f32x4 oacc[4];
#pragma unroll
  for (int i = 0; i < 4; ++i) oacc[i] = (f32x4){0.f, 0.f, 0.f, 0.f};
  float mrun = -3e38f, lrun = 0.f;
  char* sPw = sP[w];
  int ntile = (qb >> 6) + 1;

  // stage K-tile + Vt-tile (both 64 rows x 128B), pre-swizzled source (XOR c16 with row&7)
#define STAGE(BUF, KV)                                                                   \
  {                                                                                      \
    _Pragma("unroll") for (int p = 0; p < 2; ++p) {                                      \
      int idx = p * 256 + tid;                                                           \
      int row = idx >> 3;                                                                \
      int c16 = (idx & 7) ^ (row & 7);                                                   \
      gload_lds16(Kg + (size_t)((KV) + row) * 64 + c16 * 8, sK[BUF] + p * 4096 + w * 1024); \
      gload_lds16(Vg + (size_t)row * 2048 + (KV) + c16 * 8, sV[BUF] + p * 4096 + w * 1024); \
    }                                                                                    \
  }

  STAGE(0, 0);
  __syncthreads();

  for (int t = 0; t < ntile; ++t) {
    int kv = t << 6, cur = t & 1;
    if (t + 1 < ntile) STAGE(cur ^ 1, kv + 64);
    char* sKc = sK[cur];
    char* sVc = sV[cur];

    // QK^T swapped: mfma(A=K, B=Q) -> lane holds scores for q=l15, keys lg*4+r (+16*nt)
    f32x4 sf[4];
#pragma unroll
    for (int nt = 0; nt < 4; ++nt) {
      f32x4 c = (f32x4){0.f, 0.f, 0.f, 0.f};
      int key = nt * 16 + l15;
#pragma unroll
      for (int kk = 0; kk < 2; ++kk) {
        short8 kf = *(const short8*)(sKc + ((key * 128 + kk * 64 + lg * 16) ^ ((key & 7) << 4)));
        mfma_bf16(c, kf, qf[kk]);
      }
      sf[nt] = c;
    }
    if (t == ntile - 1) {  // only the diagonal tile needs masking
#pragma unroll
      for (int nt = 0; nt < 4; ++nt)
#pragma unroll
        for (int r = 0; r < 4; ++r)
          if (kv + nt * 16 + lg * 4 + r > qa) sf[nt][r] = -1e9f;
    }
    // lane-parallel online softmax (each lane owns one q-row; reduce across 4 lg-groups)
    float pm = fmaxf(fmaxf(fmaxf(sf[0][0], sf[0][1]), fmaxf(sf[0][2], sf[0][3])),
                     fmaxf(fmaxf(sf[1][0], sf[1][1]), fmaxf(sf[1][2], sf[1][3])));
    float pm2 = fmaxf(fmaxf(fmaxf(sf[2][0], sf[2][1]), fmaxf(sf[2][2], sf[2][3])),
                      fmaxf(fmaxf(sf[3][0], sf[3][1]), fmaxf(sf[3][2], sf[3][3])));
    pm = fmaxf(pm, pm2);
    pm = fmaxf(pm, __shfl_xor(pm, 16));
    pm = fmaxf(pm, __shfl_xor(pm, 32));
    float mnew = fmaxf(mrun, pm);
    int upd = mnew > mrun;
    float alpha = exp2f((mrun - mnew) * KL2E);
    mrun = mnew;
    float ps = 0.f;
#pragma unroll
    for (int nt = 0; nt < 4; ++nt)
#pragma unroll
      for (int r = 0; r < 4; ++r) {
        float pv = exp2f((sf[nt][r] - mnew) * KL2E);
        sf[nt][r] = pv;
        ps += pv;
      }
    ps += __shfl_xor(ps, 16);
    ps += __shfl_xor(ps, 32);
    lrun = lrun * alpha + ps;
    if (__any(upd)) {  // deferred rescale: skip when no lane's max grew
      float aq[4];
#pragma unroll
      for (int r = 0; r < 4; ++r) aq[r] = __shfl(alpha, lg * 4 + r);
#pragma unroll
      for (int dt = 0; dt < 4; ++dt)
#pragma unroll
        for (int r = 0; r < 4; ++r) oacc[dt][r] *= aq[r];
    }
    // pack P (bf16) -> per-wave LDS, vectorized ds_write_b64, XOR-swizzled rows
#pragma unroll
    for (int nt = 0; nt < 4; ++nt) {
      uint2 pk;
      pk.x = (u32)f2bf(sf[nt][0]) | ((u32)f2bf(sf[nt][1]) << 16);
      pk.y = (u32)f2bf(sf[nt][2]) | ((u32)f2bf(sf[nt][3]) << 16);
      *(uint2*)(sPw + ((l15 * 128 + nt * 32 + lg * 8) ^ ((l15 & 7) << 4))) = pk;
    }
    short8 pa[2];
#pragma unroll
    for (int ks = 0; ks < 2; ++ks)
      pa[ks] = *(const short8*)(sPw + ((l15 * 128 + ks * 64 + lg * 16) ^ ((l15 & 7) << 4)));
#pragma unroll
    for (int dt = 0; dt < 4; ++dt) {
      int d = dt * 16 + l15;
#pragma unroll
      for (int ks = 0; ks < 2; ++ks) {
        short8 vb = *(const short8*)(sVc + ((d * 128 + ks * 64 + lg * 16) ^ ((d & 7) << 4)));
        mfma_bf16(oacc[dt], pa[ks], vb);
      }
    }
    __syncthreads();  // drains prefetch vmcnt + guards cur-buffer overwrite next iter
  }

  float rl = 1.f / lrun;
  float lq[4];
#pragma unroll
  for (int r = 0; r < 4; ++r) lq[r] = __shfl(rl, lg * 4 + r);
  int bb = bh >> 4, h = bh & 15;
#pragma unroll
  for (int dt = 0; dt < 4; ++dt) {
    int d = dt * 16 + l15;
#pragma unroll
    for (int r = 0; r < 4; ++r) {
      int q = qr + lg * 4 + r;
      ctx[((size_t)(bb * 2048 + q)) * 1024 + h * 64 + d] = f2bf(oacc[dt][r] * lq[r]);
    }
  }
#undef STAGE
}

extern "C" void kernel_launch(void* const* d_in, const int* in_sizes, int n_in,
                              void* d_out, int out_size, void* d_ws, size_t ws_size,
                              hipStream_t stream) {
  (void)in_sizes; (void)n_in; (void)out_size; (void)ws_size;
  const float* xq = (const float*)d_in[0];
  const float* xk = (const float*)d_in[1];
  const float* xv = (const float*)d_in[2];
  const float* Wq = (const float*)d_in[4];
  const float* bq = (const float*)d_in[5];
  const float* Wk = (const float*)d_in[6];
  const float* bk = (const float*)d_in[7];
  const float* Wv = (const float*)d_in[8];
  const float* bv = (const float*)d_in[9];
  const float* Wo = (const float*)d_in[10];
  const float* bo = (const float*)d_in[11];

  char* ws = (char*)d_ws;
  u16* XQ  = (u16*)(ws);                       // 8MB, dead after QKV gemm
  u16* XK  = (u16*)(ws + ((size_t)8 << 20));   // 8MB, dead after QKV gemm
  u16* XV  = (u16*)(ws + ((size_t)16 << 20));  // 8MB
  u16* WTQ = (u16*)(ws + ((size_t)24 << 20));  // 2MB each
  u16* WTK = (u16*)(ws + ((size_t)26 << 20));
  u16* WTV = (u16*)(ws + ((size_t)28 << 20));
  u16* WTO = (u16*)(ws + ((size_t)30 << 20));
  u16* Qb  = (u16*)(ws + ((size_t)32 << 20));  // 8MB (32,2048,64) bf16
  u16* Kb  = (u16*)(ws + ((size_t)40 << 20));
  u16* Vb  = (u16*)(ws + ((size_t)48 << 20));
  u16* VT  = (u16*)(ws + ((size_t)8 << 20));   // aliases XK (dead) - (32,64,2048) bf16
  u16* CTX = (u16*)(ws);                       // aliases XQ (dead)

  k_conv_x<<<2048, 256, 0, stream>>>(xq, XQ);
  k_conv_x<<<2048, 256, 0, stream>>>(xk, XK);
  k_conv_x<<<2048, 256, 0, stream>>>(xv, XV);
  dim3 wt(16, 16);
  k_conv_wt<<<wt, 256, 0, stream>>>(Wq, WTQ);
  k_conv_wt<<<wt, 256, 0, stream>>>(Wk, WTK);
  k_conv_wt<<<wt, 256, 0, stream>>>(Wv, WTV);
  k_conv_wt<<<wt, 256, 0, stream>>>(Wo, WTO);
  dim3 gq(32, 8, 3);
  k_gemm_qkv<<<gq, 256, 0, stream>>>(XQ, XK, XV, WTQ, WTK, WTV, bq, bk, bv, Qb, Kb, Vb);
  k_rope<<<8192, 256, 0, stream>>>((u32*)Qb);
  k_rope<<<8192, 256, 0, stream>>>((u32*)Kb);
  dim3 vtg(32, 32);
  k_vtrans<<<vtg, 256, 0, stream>>>(Vb, VT);
  dim3 ag(32, 32);
  k_attn<<<ag, 256, 0, stream>>>(Qb, Kb, VT, CTX);
  dim3 gg(32, 8);
  k_gemm<1><<<gg, 256, 0, stream>>>(CTX, WTO, bo, d_out);
}

// Round 3
// 180.399 us; speedup vs baseline: 1.4024x; 1.0831x over previous
//
#include <hip/hip_runtime.h>

typedef unsigned short u16;
typedef unsigned int u32;
typedef __attribute__((ext_vector_type(8))) short short8;
typedef __attribute__((ext_vector_type(4))) float f32x4;

#define DEV static __device__ __forceinline__

DEV u16 f2bf(float x) {
  union { float f; u32 u; } v; v.f = x;
  u32 r = v.u + 0x7fffu + ((v.u >> 16) & 1u);
  return (u16)(r >> 16);
}
DEV float bf2f(u16 x) {
  union { u32 u; float f; } v; v.u = ((u32)x) << 16;
  return v.f;
}
DEV u32 cvtpk(float lo, float hi) {  // D.lo=bf16(lo), D.hi=bf16(hi), RNE
  u32 r;
  asm("v_cvt_pk_bf16_f32 %0, %1, %2" : "=v"(r) : "v"(lo), "v"(hi));
  return r;
}

DEV void gload_lds16(const void* g, void* l) {
  __builtin_amdgcn_global_load_lds(
      (__attribute__((address_space(1))) u32*)((void*)g),
      (__attribute__((address_space(3))) u32*)l, 16, 0, 0);
}

DEV void mfma_bf16(f32x4& d, short8 a, short8 b) {
  asm("v_mfma_f32_16x16x32_bf16 %0, %1, %2, %0" : "+v"(d) : "v"(a), "v"(b));
}

// ---------------- fp32 -> bf16 cast for q/k/v inputs, fused over grid.y ----------------
__global__ __launch_bounds__(256) void k_conv_x3(const float* __restrict__ x0, const float* __restrict__ x1,
                                                 const float* __restrict__ x2, u16* __restrict__ o0,
                                                 u16* __restrict__ o1, u16* __restrict__ o2) {
  int z = blockIdx.y;
  const float* in = (z == 0) ? x0 : (z == 1) ? x1 : x2;
  u16* out = (z == 0) ? o0 : (z == 1) ? o1 : o2;
  int i = blockIdx.x * 256 + threadIdx.x;
  const float4* p = (const float4*)in;
  float4 a = p[i * 2], b = p[i * 2 + 1];
  uint4 o;
  o.x = cvtpk(a.x, a.y); o.y = cvtpk(a.z, a.w);
  o.z = cvtpk(b.x, b.y); o.w = cvtpk(b.z, b.w);
  ((uint4*)out)[i] = o;
}

// ---------------- W[k][n] fp32 -> Wt[n][k] bf16, 64x64 tiles, fused over grid.z ----------------
__global__ __launch_bounds__(256) void k_conv_wt4(const float* __restrict__ W0, const float* __restrict__ W1,
                                                  const float* __restrict__ W2, const float* __restrict__ W3,
                                                  u16* __restrict__ T0, u16* __restrict__ T1,
                                                  u16* __restrict__ T2, u16* __restrict__ T3) {
  int z = blockIdx.z;
  const float* W = (z == 0) ? W0 : (z == 1) ? W1 : (z == 2) ? W2 : W3;
  u16* Wt = (z == 0) ? T0 : (z == 1) ? T1 : (z == 2) ? T2 : T3;
  __shared__ u16 tile[64][65];
  int t = threadIdx.x;
  int k0 = blockIdx.x * 64, n0 = blockIdx.y * 64;
  int rr = t >> 4, cc = (t & 15) * 4;
#pragma unroll
  for (int i = 0; i < 4; ++i) {
    int r = rr + i * 16;
    float4 v = *(const float4*)&W[(size_t)(k0 + r) * 1024 + n0 + cc];
    tile[r][cc + 0] = f2bf(v.x); tile[r][cc + 1] = f2bf(v.y);
    tile[r][cc + 2] = f2bf(v.z); tile[r][cc + 3] = f2bf(v.w);
  }
  __syncthreads();
#pragma unroll
  for (int i = 0; i < 4; ++i) {
    int n = rr + i * 16;
    u16 a0 = tile[cc + 0][n], a1 = tile[cc + 1][n], a2 = tile[cc + 2][n], a3 = tile[cc + 3][n];
    uint2 pk;
    pk.x = (u32)a0 | ((u32)a1 << 16);
    pk.y = (u32)a2 | ((u32)a3 << 16);
    *(uint2*)&Wt[(size_t)(n0 + n) * 1024 + k0 + cc] = pk;
  }
}

// ---------------- V (b,h,s,d) bf16 -> Vt (b,h,d,s) bf16, 64x64 tiles ----------------
__global__ __launch_bounds__(256) void k_vtrans(const u16* __restrict__ in, u16* __restrict__ out) {
  __shared__ u16 tile[64][65];
  int t = threadIdx.x;
  int s0 = blockIdx.x * 64;
  size_t base = (size_t)blockIdx.y * 131072;
#pragma unroll
  for (int p = 0; p < 2; ++p) {
    int i = p * 256 + t;
    int r = i >> 3, c = i & 7;
    short8 v = *(const short8*)(in + base + (size_t)(s0 + r) * 64 + c * 8);
#pragma unroll
    for (int j = 0; j < 8; ++j) tile[r][c * 8 + j] = (u16)(unsigned short)v[j];
  }
  __syncthreads();
#pragma unroll
  for (int p = 0; p < 2; ++p) {
    int i = p * 256 + t;
    int d = i >> 3, c = i & 7;
    short8 o;
#pragma unroll
    for (int j = 0; j < 8; ++j) o[j] = (short)tile[c * 8 + j][d];
    *(short8*)(out + base + (size_t)d * 2048 + s0 + c * 8) = o;
  }
}

// ---------------- GEMM core, BK=64, XOR-swizzled LDS (2-way conflict = free) ----------------
// Stages 128x64 bf16 A and B^T tiles; global source pre-swizzled (c8 ^= row&7),
// ds_read applies the same involution.
#define GEMM_BODY(A_, Bt_)                                                                       \
  __shared__ __align__(16) char sA[16384];                                                       \
  __shared__ __align__(16) char sB[16384];                                                       \
  int tid = threadIdx.x, lane = tid & 63, w = tid >> 6;                                          \
  int l15 = lane & 15, lg = lane >> 4;                                                           \
  int bm = blockIdx.x * 128, bn = blockIdx.y * 128;                                              \
  int wm = (w >> 1) * 64, wn = (w & 1) * 64;                                                     \
  f32x4 acc[4][4];                                                                               \
  _Pragma("unroll") for (int i = 0; i < 4; ++i)                                                  \
      _Pragma("unroll") for (int j = 0; j < 4; ++j) acc[i][j] = (f32x4){0.f, 0.f, 0.f, 0.f};     \
  for (int kt = 0; kt < 16; ++kt) {                                                              \
    _Pragma("unroll") for (int p = 0; p < 4; ++p) {                                              \
      int idx = p * 256 + tid;                                                                   \
      int row = idx >> 3;                                                                        \
      int c8 = (idx & 7) ^ (row & 7);                                                            \
      gload_lds16(A_ + (size_t)(bm + row) * 1024 + kt * 64 + c8 * 8, sA + p * 4096 + w * 1024);  \
      gload_lds16(Bt_ + (size_t)(bn + row) * 1024 + kt * 64 + c8 * 8, sB + p * 4096 + w * 1024); \
    }                                                                                            \
    __syncthreads();                                                                             \
    short8 af[4][2], bf[4][2];                                                                   \
    _Pragma("unroll") for (int i = 0; i < 4; ++i) _Pragma("unroll") for (int s = 0; s < 2; ++s) { \
      int cs = ((s * 4 + lg) ^ (l15 & 7)) * 16;                                                  \
      af[i][s] = *(const short8*)(sA + (wm + i * 16 + l15) * 128 + cs);                          \
      bf[i][s] = *(const short8*)(sB + (wn + i * 16 + l15) * 128 + cs);                          \
    }                                                                                            \
    _Pragma("unroll") for (int s = 0; s < 2; ++s)                                                \
        _Pragma("unroll") for (int i = 0; i < 4; ++i)                                            \
            _Pragma("unroll") for (int j = 0; j < 4; ++j) mfma_bf16(acc[i][j], af[i][s], bf[j][s]); \
    __syncthreads();                                                                             \
  }

// MODE 0: write bf16 to (b,h,s,d) head-split layout.  MODE 1: write fp32 row-major.
template <int MODE>
__global__ __launch_bounds__(256) void k_gemm(const u16* __restrict__ A, const u16* __restrict__ Bt,
                                              const float* __restrict__ bias, void* __restrict__ dst) {
  GEMM_BODY(A, Bt)
  float bv[4];
#pragma unroll
  for (int j = 0; j < 4; ++j) bv[j] = bias[bn + wn + j * 16 + l15];
#pragma unroll
  for (int i = 0; i < 4; ++i) {
#pragma unroll
    for (int j = 0; j < 4; ++j) {
#pragma unroll
      for (int r = 0; r < 4; ++r) {
        int m = bm + wm + i * 16 + lg * 4 + r;
        int n = bn + wn + j * 16 + l15;
        float v = acc[i][j][r] + bv[j];
        if (MODE == 0) {
          int bb = m >> 11, s = m & 2047, h = n >> 6, d = n & 63;
          ((u16*)dst)[(((size_t)(bb * 16 + h)) * 2048 + s) * 64 + d] = f2bf(v);
        } else {
          ((float*)dst)[(size_t)m * 1024 + n] = v;
        }
      }
    }
  }
}

// QKV fused over blockIdx.z
__global__ __launch_bounds__(256) void k_gemm_qkv(const u16* __restrict__ Aq, const u16* __restrict__ Ak,
                                                  const u16* __restrict__ Av, const u16* __restrict__ Wq,
                                                  const u16* __restrict__ Wk, const u16* __restrict__ Wv,
                                                  const float* __restrict__ bq, const float* __restrict__ bk,
                                                  const float* __restrict__ bv, u16* __restrict__ Qo,
                                                  u16* __restrict__ Ko, u16* __restrict__ Vo) {
  int z = blockIdx.z;
  const u16* A = (z == 0) ? Aq : (z == 1) ? Ak : Av;
  const u16* Bt = (z == 0) ? Wq : (z == 1) ? Wk : Wv;
  const float* bias = (z == 0) ? bq : (z == 1) ? bk : bv;
  u16* dst = (z == 0) ? Qo : (z == 1) ? Ko : Vo;
  GEMM_BODY(A, Bt)
  float bvv[4];
#pragma unroll
  for (int j = 0; j < 4; ++j) bvv[j] = bias[bn + wn + j * 16 + l15];
#pragma unroll
  for (int i = 0; i < 4; ++i) {
#pragma unroll
    for (int j = 0; j < 4; ++j) {
#pragma unroll
      for (int r = 0; r < 4; ++r) {
        int m = bm + wm + i * 16 + lg * 4 + r;
        int n = bn + wn + j * 16 + l15;
        float v = acc[i][j][r] + bvv[j];
        int bb = m >> 11, s = m & 2047, h = n >> 6, d = n & 63;
        dst[(((size_t)(bb * 16 + h)) * 2048 + s) * 64 + d] = f2bf(v);
      }
    }
  }
}

// ---------------- RoPE in-place, Q and K in one contiguous 16MB region ----------------
__global__ __launch_bounds__(256) void k_rope(u32* __restrict__ buf) {
  int p = blockIdx.x * 256 + threadIdx.x;  // 4M pairs (Q then K)
  u32 u = buf[p];
  float xe = bf2f((u16)(u & 0xffffu));
  float xo = bf2f((u16)(u >> 16));
  int dp = p & 31;
  int s = (p >> 5) & 2047;
  float theta = exp2f((float)dp * (-2.0f / 64.0f) * 13.287712379549449f);  // 10000^(-2i/64)
  float ang = (float)s * theta;
  float sn, cs;
  sincosf(ang, &sn, &cs);
  float re = xe * cs - xo * sn;
  float ro = xe * sn + xo * cs;
  buf[p] = (u32)f2bf(re) | ((u32)f2bf(ro) << 16);
}

// ---------------- causal flash attention, QBLK=128/block, swapped-QK^T ----------------
// grid (16 reversed-qb, 32 bh); 4 waves/block, 32 q-rows per wave (2 x 16-row subtiles)
__global__ __launch_bounds__(256, 3) void k_attn(const u16* __restrict__ Q, const u16* __restrict__ K,
                                                 const u16* __restrict__ Vt, u16* __restrict__ ctx) {
  __shared__ __align__(16) char sK[2][8192];
  __shared__ __align__(16) char sV[2][8192];
  __shared__ __align__(16) char sP[4][2][2048];
  const float KL2E = 0.18033688011112042f;  // (1/8) * log2(e)
  int tid = threadIdx.x, lane = tid & 63, w = tid >> 6;
  int l15 = lane & 15, lg = lane >> 4;
  int qb = (15 - blockIdx.x) * 128;  // heavy blocks first
  int bh = blockIdx.y;
  const u16* Qg = Q + (size_t)bh * 131072;
  const u16* Kg = K + (size_t)bh * 131072;
  const u16* Vg = Vt + (size_t)bh * 131072;
  int qr0 = qb + w * 32;

  short8 qf[2][2];
#pragma unroll
  for (int g = 0; g < 2; ++g)
#pragma unroll
    for (int kk = 0; kk < 2; ++kk)
      qf[g][kk] = *(const short8*)(Qg + (size_t)(qr0 + 16 * g + l15) * 64 + kk * 32 + lg * 8);

  f32x4 oacc[2][4];
#pragma unroll
  for (int g = 0; g < 2; ++g)
#pragma unroll
    for (int i = 0; i < 4; ++i) oacc[g][i] = (f32x4){0.f, 0.f, 0.f, 0.f};
  float mrun[2] = {-3e38f, -3e38f}, lrun[2] = {0.f, 0.f};
  int ntile = (qb >> 6) + 2;

  // stage K-tile + Vt-tile (both 64 rows x 128B), pre-swizzled source (XOR c16 with row&7)
#define STAGE(BUF, KV)                                                                        \
  {                                                                                           \
    _Pragma("unroll") for (int p = 0; p < 2; ++p) {                                           \
      int idx = p * 256 + tid;                                                                \
      int row = idx >> 3;                                                                     \
      int c16 = (idx & 7) ^ (row & 7);                                                        \
      gload_lds16(Kg + (size_t)((KV) + row) * 64 + c16 * 8, sK[BUF] + p * 4096 + w * 1024);   \
      gload_lds16(Vg + (size_t)row * 2048 + (KV) + c16 * 8, sV[BUF] + p * 4096 + w * 1024);   \
    }                                                                                         \
  }

  STAGE(0, 0);
  __syncthreads();

  for (int t = 0; t < ntile; ++t) {
    int kv = t << 6, cur = t & 1;
    if (t + 1 < ntile) STAGE(cur ^ 1, kv + 64);
    char* sKc = sK[cur];
    char* sVc = sV[cur];

#pragma unroll
    for (int g = 0; g < 2; ++g) {
      int qg = qr0 + 16 * g;
      if (kv > qg + 15) continue;  // wave-uniform skip of fully-masked tiles
      // QK^T swapped: mfma(A=K, B=Q) -> lane holds scores for q-col=l15, key-row=lg*4+r
      f32x4 sf[4];
#pragma unroll
      for (int nt = 0; nt < 4; ++nt) {
        f32x4 c = (f32x4){0.f, 0.f, 0.f, 0.f};
        int key = nt * 16 + l15;
#pragma unroll
        for (int kk = 0; kk < 2; ++kk) {
          short8 kf = *(const short8*)(sKc + ((key * 128 + kk * 64 + lg * 16) ^ ((key & 7) << 4)));
          mfma_bf16(c, kf, qf[g][kk]);
        }
        sf[nt] = c;
      }
      if (kv + 63 > qg) {  // exactly the diagonal tile of this subtile
        int qa = qg + l15;
#pragma unroll
        for (int nt = 0; nt < 4; ++nt)
#pragma unroll
          for (int r = 0; r < 4; ++r)
            if (kv + nt * 16 + lg * 4 + r > qa) sf[nt][r] = -1e9f;
      }
      // lane-parallel online softmax (lane owns q-row l15; reduce over 4 lg-groups)
      float pm = fmaxf(fmaxf(fmaxf(sf[0][0], sf[0][1]), fmaxf(sf[0][2], sf[0][3])),
                       fmaxf(fmaxf(sf[1][0], sf[1][1]), fmaxf(sf[1][2], sf[1][3])));
      float pm2 = fmaxf(fmaxf(fmaxf(sf[2][0], sf[2][1]), fmaxf(sf[2][2], sf[2][3])),
                        fmaxf(fmaxf(sf[3][0], sf[3][1]), fmaxf(sf[3][2], sf[3][3])));
      pm = fmaxf(pm, pm2);
      pm = fmaxf(pm, __shfl_xor(pm, 16));
      pm = fmaxf(pm, __shfl_xor(pm, 32));
      float mnew = fmaxf(mrun[g], pm);
      int upd = mnew > mrun[g];
      float alpha = exp2f((mrun[g] - mnew) * KL2E);
      mrun[g] = mnew;
      float ps = 0.f;
#pragma unroll
      for (int nt = 0; nt < 4; ++nt)
#pragma unroll
        for (int r = 0; r < 4; ++r) {
          float pv = exp2f((sf[nt][r] - mnew) * KL2E);
          sf[nt][r] = pv;
          ps += pv;
        }
      ps += __shfl_xor(ps, 16);
      ps += __shfl_xor(ps, 32);
      lrun[g] = lrun[g] * alpha + ps;
      if (__any(upd)) {  // deferred rescale
        float aq[4];
#pragma unroll
        for (int r = 0; r < 4; ++r) aq[r] = __shfl(alpha, lg * 4 + r);
#pragma unroll
        for (int dt = 0; dt < 4; ++dt)
#pragma unroll
          for (int r = 0; r < 4; ++r) oacc[g][dt][r] *= aq[r];
      }
      // pack P (bf16 via cvt_pk) -> per-wave LDS, XOR-swizzled rows
      char* sPw = sP[w][g];
#pragma unroll
      for (int nt = 0; nt < 4; ++nt) {
        uint2 pk;
        pk.x = cvtpk(sf[nt][0], sf[nt][1]);
        pk.y = cvtpk(sf[nt][2], sf[nt][3]);
        *(uint2*)(sPw + ((l15 * 128 + nt * 32 + lg * 8) ^ ((l15 & 7) << 4))) = pk;
      }
      short8 pa[2];
#pragma unroll
      for (int ks = 0; ks < 2; ++ks)
        pa[ks] = *(const short8*)(sPw + ((l15 * 128 + ks * 64 + lg * 16) ^ ((l15 & 7) << 4)));
#pragma unroll
      for (int dt = 0; dt < 4; ++dt) {
        int d = dt * 16 + l15;
#pragma unroll
        for (int ks = 0; ks < 2; ++ks) {
          short8 vb = *(const short8*)(sVc + ((d * 128 + ks * 64 + lg * 16) ^ ((d & 7) << 4)));
          mfma_bf16(oacc[g][dt], pa[ks], vb);
        }
      }
    }
    __syncthreads();  // drains prefetch vmcnt + guards cur-buffer overwrite next iter
  }

  int bb = bh >> 4, h = bh & 15;
#pragma unroll
  for (int g = 0; g < 2; ++g) {
    float rl = 1.f / lrun[g];
    float lq[4];
#pragma unroll
    for (int r = 0; r < 4; ++r) lq[r] = __shfl(rl, lg * 4 + r);
#pragma unroll
    for (int dt = 0; dt < 4; ++dt) {
      int d = dt * 16 + l15;
#pragma unroll
      for (int r = 0; r < 4; ++r) {
        int q = qr0 + 16 * g + lg * 4 + r;
        ctx[((size_t)(bb * 2048 + q)) * 1024 + h * 64 + d] = f2bf(oacc[g][dt][r] * lq[r]);
      }
    }
  }
#undef STAGE
}

extern "C" void kernel_launch(void* const* d_in, const int* in_sizes, int n_in,
                              void* d_out, int out_size, void* d_ws, size_t ws_size,
                              hipStream_t stream) {
  (void)in_sizes; (void)n_in; (void)out_size; (void)ws_size;
  const float* xq = (const float*)d_in[0];
  const float* xk = (const float*)d_in[1];
  const float* xv = (const float*)d_in[2];
  const float* Wq = (const float*)d_in[4];
  const float* bq = (const float*)d_in[5];
  const float* Wk = (const float*)d_in[6];
  const float* bk = (const float*)d_in[7];
  const float* Wv = (const float*)d_in[8];
  const float* bv = (const float*)d_in[9];
  const float* Wo = (const float*)d_in[10];
  const float* bo = (const float*)d_in[11];

  char* ws = (char*)d_ws;
  u16* XQ  = (u16*)(ws);                       // 8MB, dead after QKV gemm
  u16* XK  = (u16*)(ws + ((size_t)8 << 20));   // 8MB, dead after QKV gemm
  u16* XV  = (u16*)(ws + ((size_t)16 << 20));  // 8MB
  u16* WTQ = (u16*)(ws + ((size_t)24 << 20));  // 2MB each
  u16* WTK = (u16*)(ws + ((size_t)26 << 20));
  u16* WTV = (u16*)(ws + ((size_t)28 << 20));
  u16* WTO = (u16*)(ws + ((size_t)30 << 20));
  u16* Qb  = (u16*)(ws + ((size_t)32 << 20));  // 8MB (32,2048,64) bf16
  u16* Kb  = (u16*)(ws + ((size_t)40 << 20));  // contiguous after Qb (rope does both)
  u16* Vb  = (u16*)(ws + ((size_t)48 << 20));
  u16* VT  = (u16*)(ws + ((size_t)8 << 20));   // aliases XK (dead) - (32,64,2048) bf16
  u16* CTX = (u16*)(ws);                       // aliases XQ (dead)

  dim3 cx(2048, 3);
  k_conv_x3<<<cx, 256, 0, stream>>>(xq, xk, xv, XQ, XK, XV);
  dim3 wt(16, 16, 4);
  k_conv_wt4<<<wt, 256, 0, stream>>>(Wq, Wk, Wv, Wo, WTQ, WTK, WTV, WTO);
  dim3 gq(32, 8, 3);
  k_gemm_qkv<<<gq, 256, 0, stream>>>(XQ, XK, XV, WTQ, WTK, WTV, bq, bk, bv, Qb, Kb, Vb);
  k_rope<<<16384, 256, 0, stream>>>((u32*)Qb);  // Q and K in one contiguous region
  dim3 vtg(32, 32);
  k_vtrans<<<vtg, 256, 0, stream>>>(Vb, VT);
  dim3 ag(16, 32);
  k_attn<<<ag, 256, 0, stream>>>(Qb, Kb, VT, CTX);
  dim3 gg(32, 8);
  k_gemm<1><<<gg, 256, 0, stream>>>(CTX, WTO, bo, d_out);
}

// Round 4
// 170.703 us; speedup vs baseline: 1.4820x; 1.0568x over previous
//
#include <hip/hip_runtime.h>

typedef unsigned short u16;
typedef unsigned int u32;
typedef __attribute__((ext_vector_type(8))) short short8;
typedef __attribute__((ext_vector_type(4))) float f32x4;
typedef __attribute__((ext_vector_type(16))) float f32x16;

#define DEV static __device__ __forceinline__

DEV u16 f2bf(float x) {
  union { float f; u32 u; } v; v.f = x;
  u32 r = v.u + 0x7fffu + ((v.u >> 16) & 1u);
  return (u16)(r >> 16);
}
DEV float bf2f(u16 x) {
  union { u32 u; float f; } v; v.u = ((u32)x) << 16;
  return v.f;
}
DEV u32 cvtpk(float lo, float hi) {  // D.lo=bf16(lo), D.hi=bf16(hi), RNE
  u32 r;
  asm("v_cvt_pk_bf16_f32 %0, %1, %2" : "=v"(r) : "v"(lo), "v"(hi));
  return r;
}
DEV void swap32(u32& a, u32& b) {  // a' = [a.lo32 | b.lo32], b' = [a.hi32 | b.hi32]
  asm("v_permlane32_swap_b32 %0, %1" : "+v"(a), "+v"(b));
}

DEV void gload_lds16(const void* g, void* l) {
  __builtin_amdgcn_global_load_lds(
      (__attribute__((address_space(1))) u32*)((void*)g),
      (__attribute__((address_space(3))) u32*)l, 16, 0, 0);
}

DEV void mfma_bf16(f32x4& d, short8 a, short8 b) {
  asm("v_mfma_f32_16x16x32_bf16 %0, %1, %2, %0" : "+v"(d) : "v"(a), "v"(b));
}
DEV void mfma32(f32x16& d, short8 a, short8 b) {
  asm("v_mfma_f32_32x32x16_bf16 %0, %1, %2, %0" : "+v"(d) : "v"(a), "v"(b));
}

// ---------------- fp32 -> bf16 cast for q/k/v inputs, fused over grid.y ----------------
__global__ __launch_bounds__(256) void k_conv_x3(const float* __restrict__ x0, const float* __restrict__ x1,
                                                 const float* __restrict__ x2, u16* __restrict__ o0,
                                                 u16* __restrict__ o1, u16* __restrict__ o2) {
  int z = blockIdx.y;
  const float* in = (z == 0) ? x0 : (z == 1) ? x1 : x2;
  u16* out = (z == 0) ? o0 : (z == 1) ? o1 : o2;
  int i = blockIdx.x * 256 + threadIdx.x;
  const float4* p = (const float4*)in;
  float4 a = p[i * 2], b = p[i * 2 + 1];
  uint4 o;
  o.x = cvtpk(a.x, a.y); o.y = cvtpk(a.z, a.w);
  o.z = cvtpk(b.x, b.y); o.w = cvtpk(b.z, b.w);
  ((uint4*)out)[i] = o;
}

// ---------------- W[k][n] fp32 -> Wt[n][k] bf16, 64x64 tiles, fused over grid.z ----------------
__global__ __launch_bounds__(256) void k_conv_wt4(const float* __restrict__ W0, const float* __restrict__ W1,
                                                  const float* __restrict__ W2, const float* __restrict__ W3,
                                                  u16* __restrict__ T0, u16* __restrict__ T1,
                                                  u16* __restrict__ T2, u16* __restrict__ T3) {
  int z = blockIdx.z;
  const float* W = (z == 0) ? W0 : (z == 1) ? W1 : (z == 2) ? W2 : W3;
  u16* Wt = (z == 0) ? T0 : (z == 1) ? T1 : (z == 2) ? T2 : T3;
  __shared__ u16 tile[64][65];
  int t = threadIdx.x;
  int k0 = blockIdx.x * 64, n0 = blockIdx.y * 64;
  int rr = t >> 4, cc = (t & 15) * 4;
#pragma unroll
  for (int i = 0; i < 4; ++i) {
    int r = rr + i * 16;
    float4 v = *(const float4*)&W[(size_t)(k0 + r) * 1024 + n0 + cc];
    tile[r][cc + 0] = f2bf(v.x); tile[r][cc + 1] = f2bf(v.y);
    tile[r][cc + 2] = f2bf(v.z); tile[r][cc + 3] = f2bf(v.w);
  }
  __syncthreads();
#pragma unroll
  for (int i = 0; i < 4; ++i) {
    int n = rr + i * 16;
    u16 a0 = tile[cc + 0][n], a1 = tile[cc + 1][n], a2 = tile[cc + 2][n], a3 = tile[cc + 3][n];
    uint2 pk;
    pk.x = (u32)a0 | ((u32)a1 << 16);
    pk.y = (u32)a2 | ((u32)a3 << 16);
    *(uint2*)&Wt[(size_t)(n0 + n) * 1024 + k0 + cc] = pk;
  }
}

// ---------------- V (b,h,s,d) bf16 -> Vt (b,h,d,s) bf16, 64x64 tiles ----------------
__global__ __launch_bounds__(256) void k_vtrans(const u16* __restrict__ in, u16* __restrict__ out) {
  __shared__ u16 tile[64][65];
  int t = threadIdx.x;
  int s0 = blockIdx.x * 64;
  size_t base = (size_t)blockIdx.y * 131072;
#pragma unroll
  for (int p = 0; p < 2; ++p) {
    int i = p * 256 + t;
    int r = i >> 3, c = i & 7;
    short8 v = *(const short8*)(in + base + (size_t)(s0 + r) * 64 + c * 8);
#pragma unroll
    for (int j = 0; j < 8; ++j) tile[r][c * 8 + j] = (u16)(unsigned short)v[j];
  }
  __syncthreads();
#pragma unroll
  for (int p = 0; p < 2; ++p) {
    int i = p * 256 + t;
    int d = i >> 3, c = i & 7;
    short8 o;
#pragma unroll
    for (int j = 0; j < 8; ++j) o[j] = (short)tile[c * 8 + j][d];
    *(short8*)(out + base + (size_t)d * 2048 + s0 + c * 8) = o;
  }
}

// ---------------- GEMM core, BK=64, XOR-swizzled LDS (2-way conflict = free) ----------------
#define GEMM_BODY(A_, Bt_)                                                                       \
  __shared__ __align__(16) char sA[16384];                                                       \
  __shared__ __align__(16) char sB[16384];                                                       \
  int tid = threadIdx.x, lane = tid & 63, w = tid >> 6;                                          \
  int l15 = lane & 15, lg = lane >> 4;                                                           \
  int bm = blockIdx.x * 128, bn = blockIdx.y * 128;                                              \
  int wm = (w >> 1) * 64, wn = (w & 1) * 64;                                                     \
  f32x4 acc[4][4];                                                                               \
  _Pragma("unroll") for (int i = 0; i < 4; ++i)                                                  \
      _Pragma("unroll") for (int j = 0; j < 4; ++j) acc[i][j] = (f32x4){0.f, 0.f, 0.f, 0.f};     \
  for (int kt = 0; kt < 16; ++kt) {                                                              \
    _Pragma("unroll") for (int p = 0; p < 4; ++p) {                                              \
      int idx = p * 256 + tid;                                                                   \
      int row = idx >> 3;                                                                        \
      int c8 = (idx & 7) ^ (row & 7);                                                            \
      gload_lds16(A_ + (size_t)(bm + row) * 1024 + kt * 64 + c8 * 8, sA + p * 4096 + w * 1024);  \
      gload_lds16(Bt_ + (size_t)(bn + row) * 1024 + kt * 64 + c8 * 8, sB + p * 4096 + w * 1024); \
    }                                                                                            \
    __syncthreads();                                                                             \
    short8 af[4][2], bf[4][2];                                                                   \
    _Pragma("unroll") for (int i = 0; i < 4; ++i) _Pragma("unroll") for (int s = 0; s < 2; ++s) { \
      int cs = ((s * 4 + lg) ^ (l15 & 7)) * 16;                                                  \
      af[i][s] = *(const short8*)(sA + (wm + i * 16 + l15) * 128 + cs);                          \
      bf[i][s] = *(const short8*)(sB + (wn + i * 16 + l15) * 128 + cs);                          \
    }                                                                                            \
    _Pragma("unroll") for (int s = 0; s < 2; ++s)                                                \
        _Pragma("unroll") for (int i = 0; i < 4; ++i)                                            \
            _Pragma("unroll") for (int j = 0; j < 4; ++j) mfma_bf16(acc[i][j], af[i][s], bf[j][s]); \
    __syncthreads();                                                                             \
  }

// MODE 0: write bf16 to (b,h,s,d) head-split layout.  MODE 1: write fp32 row-major.
template <int MODE>
__global__ __launch_bounds__(256) void k_gemm(const u16* __restrict__ A, const u16* __restrict__ Bt,
                                              const float* __restrict__ bias, void* __restrict__ dst) {
  GEMM_BODY(A, Bt)
  float bv[4];
#pragma unroll
  for (int j = 0; j < 4; ++j) bv[j] = bias[bn + wn + j * 16 + l15];
#pragma unroll
  for (int i = 0; i < 4; ++i) {
#pragma unroll
    for (int j = 0; j < 4; ++j) {
#pragma unroll
      for (int r = 0; r < 4; ++r) {
        int m = bm + wm + i * 16 + lg * 4 + r;
        int n = bn + wn + j * 16 + l15;
        float v = acc[i][j][r] + bv[j];
        if (MODE == 0) {
          int bb = m >> 11, s = m & 2047, h = n >> 6, d = n & 63;
          ((u16*)dst)[(((size_t)(bb * 16 + h)) * 2048 + s) * 64 + d] = f2bf(v);
        } else {
          ((float*)dst)[(size_t)m * 1024 + n] = v;
        }
      }
    }
  }
}

// QKV fused over blockIdx.z
__global__ __launch_bounds__(256) void k_gemm_qkv(const u16* __restrict__ Aq, const u16* __restrict__ Ak,
                                                  const u16* __restrict__ Av, const u16* __restrict__ Wq,
                                                  const u16* __restrict__ Wk, const u16* __restrict__ Wv,
                                                  const float* __restrict__ bq, const float* __restrict__ bk,
                                                  const float* __restrict__ bv, u16* __restrict__ Qo,
                                                  u16* __restrict__ Ko, u16* __restrict__ Vo) {
  int z = blockIdx.z;
  const u16* A = (z == 0) ? Aq : (z == 1) ? Ak : Av;
  const u16* Bt = (z == 0) ? Wq : (z == 1) ? Wk : Wv;
  const float* bias = (z == 0) ? bq : (z == 1) ? bk : bv;
  u16* dst = (z == 0) ? Qo : (z == 1) ? Ko : Vo;
  GEMM_BODY(A, Bt)
  float bvv[4];
#pragma unroll
  for (int j = 0; j < 4; ++j) bvv[j] = bias[bn + wn + j * 16 + l15];
#pragma unroll
  for (int i = 0; i < 4; ++i) {
#pragma unroll
    for (int j = 0; j < 4; ++j) {
#pragma unroll
      for (int r = 0; r < 4; ++r) {
        int m = bm + wm + i * 16 + lg * 4 + r;
        int n = bn + wn + j * 16 + l15;
        float v = acc[i][j][r] + bvv[j];
        int bb = m >> 11, s = m & 2047, h = n >> 6, d = n & 63;
        dst[(((size_t)(bb * 16 + h)) * 2048 + s) * 64 + d] = f2bf(v);
      }
    }
  }
}

// ---------------- RoPE in-place, Q and K in one contiguous 16MB region ----------------
__global__ __launch_bounds__(256) void k_rope(u32* __restrict__ buf) {
  int p = blockIdx.x * 256 + threadIdx.x;  // 4M pairs (Q then K)
  u32 u = buf[p];
  float xe = bf2f((u16)(u & 0xffffu));
  float xo = bf2f((u16)(u >> 16));
  int dp = p & 31;
  int s = (p >> 5) & 2047;
  float theta = exp2f((float)dp * (-2.0f / 64.0f) * 13.287712379549449f);  // 10000^(-2i/64)
  float ang = (float)s * theta;
  float sn, cs;
  sincosf(ang, &sn, &cs);
  float re = xe * cs - xo * sn;
  float ro = xe * sn + xo * cs;
  buf[p] = (u32)f2bf(re) | ((u32)f2bf(ro) << 16);
}

// ---------------- causal flash attention, 32x32 MFMA, 1 wave/block, no LDS ----------------
// 2048 blocks x 64 thr. Wave owns 32 q-rows. Swapped QK^T: lane = q-col (lane&31),
// P in-register redistribution via cvt_pk + permlane32_swap (T12). K/V read direct
// global->reg (L2-resident; bh clustered per XCD via blockIdx swizzle).
__global__ __launch_bounds__(64, 2) void k_attn(const u16* __restrict__ Q, const u16* __restrict__ K,
                                                const u16* __restrict__ Vt, u16* __restrict__ ctx) {
  const float KL2E = 0.18033688011112042f;  // (1/8) * log2(e)
  int id = blockIdx.x;
  int bh = ((id >> 3) & 3) * 8 + (id & 7);  // XCD-cluster: bh%8 == id%8
  int qt = 63 - (id >> 5);                  // heavy q-tiles first
  int lane = threadIdx.x;
  int q31 = lane & 31, h = lane >> 5;
  const u16* Qg = Q + (size_t)bh * 131072;
  const u16* Kg = K + (size_t)bh * 131072;
  const u16* Vg = Vt + (size_t)bh * 131072;
  int qrow = qt * 32 + q31;

  short8 qf[4];
#pragma unroll
  for (int m = 0; m < 4; ++m)
    qf[m] = *(const short8*)(Qg + (size_t)qrow * 64 + m * 16 + h * 8);

  f32x16 o0 = {0}, o1 = {0};
#pragma unroll
  for (int r = 0; r < 16; ++r) { o0[r] = 0.f; o1[r] = 0.f; }
  float mrun = -3e38f, lrun = 0.f;
  int ntile = (qt >> 1) + 1;

  for (int t = 0; t < ntile; ++t) {
    int kv = t << 6;
    // K fragments: A[row=key(lane&31)][k = d-slice m*16+h*8..+7]
    short8 kf0[4], kf1[4];
#pragma unroll
    for (int m = 0; m < 4; ++m) {
      kf0[m] = *(const short8*)(Kg + (size_t)(kv + q31) * 64 + m * 16 + h * 8);
      kf1[m] = *(const short8*)(Kg + (size_t)(kv + 32 + q31) * 64 + m * 16 + h * 8);
    }
    f32x16 pA, pB;
#pragma unroll
    for (int r = 0; r < 16; ++r) { pA[r] = 0.f; pB[r] = 0.f; }
#pragma unroll
    for (int m = 0; m < 4; ++m) mfma32(pA, kf0[m], qf[m]);
#pragma unroll
    for (int m = 0; m < 4; ++m) mfma32(pB, kf1[m], qf[m]);

    if (t == ntile - 1) {  // diagonal tile: mask key > q
#pragma unroll
      for (int r = 0; r < 16; ++r) {
        int keyA = kv + (r & 3) + 8 * (r >> 2) + 4 * h;
        if (keyA > qrow) pA[r] = -1e9f;
        if (keyA + 32 > qrow) pB[r] = -1e9f;
      }
    }
    // online softmax: lane owns q-row q31 (16 keys here, other 16 in lane^32)
    float pm = pA[0];
#pragma unroll
    for (int r = 1; r < 16; ++r) pm = fmaxf(pm, pA[r]);
#pragma unroll
    for (int r = 0; r < 16; ++r) pm = fmaxf(pm, pB[r]);
    pm = fmaxf(pm, __shfl_xor(pm, 32));
    float mnew = fmaxf(mrun, pm);
    int upd = pm > mrun;
    float alpha = exp2f((mrun - mnew) * KL2E);
    mrun = mnew;
    float ps = 0.f;
#pragma unroll
    for (int r = 0; r < 16; ++r) {
      pA[r] = exp2f((pA[r] - mnew) * KL2E);
      ps += pA[r];
    }
#pragma unroll
    for (int r = 0; r < 16; ++r) {
      pB[r] = exp2f((pB[r] - mnew) * KL2E);
      ps += pB[r];
    }
    ps += __shfl_xor(ps, 32);
    lrun = lrun * alpha + ps;
    if (__any(upd)) {
#pragma unroll
      for (int r = 0; r < 16; ++r) { o0[r] *= alpha; o1[r] *= alpha; }
    }
    // V^T fragments: A[row=d(lane&31)][k = key m*16+h*8..+7]
    short8 vf0[4], vf1[4];
#pragma unroll
    for (int m = 0; m < 4; ++m) {
      vf0[m] = *(const short8*)(Vg + (size_t)q31 * 2048 + kv + m * 16 + h * 8);
      vf1[m] = *(const short8*)(Vg + (size_t)(32 + q31) * 2048 + kv + m * 16 + h * 8);
    }
    // P -> bf16 B-frags via cvt_pk + permlane32_swap; PV accumulate
#pragma unroll
    for (int m = 0; m < 4; ++m) {
      int mlow = 8 * (m & 1);
      u32 u0, u1, v0, v1;
      if (m < 2) {
        u0 = cvtpk(pA[mlow + 0], pA[mlow + 1]);
        u1 = cvtpk(pA[mlow + 2], pA[mlow + 3]);
        v0 = cvtpk(pA[mlow + 4], pA[mlow + 5]);
        v1 = cvtpk(pA[mlow + 6], pA[mlow + 7]);
      } else {
        u0 = cvtpk(pB[mlow + 0], pB[mlow + 1]);
        u1 = cvtpk(pB[mlow + 2], pB[mlow + 3]);
        v0 = cvtpk(pB[mlow + 4], pB[mlow + 5]);
        v1 = cvtpk(pB[mlow + 6], pB[mlow + 7]);
      }
      swap32(u0, v0);
      swap32(u1, v1);
      union { u32 w[4]; short8 s; } pf;
      pf.w[0] = u0; pf.w[1] = u1; pf.w[2] = v0; pf.w[3] = v1;
      mfma32(o0, vf0[m], pf.s);
      mfma32(o1, vf1[m], pf.s);
    }
  }

  float rl = 1.f / lrun;
  int bb = bh >> 4, hh = bh & 15;
  u16* base = ctx + ((size_t)(bb * 2048 + qrow)) * 1024 + hh * 64;
#pragma unroll
  for (int r = 0; r < 4; ++r) {
    uint2 pk;
    pk.x = cvtpk(o0[4 * r + 0] * rl, o0[4 * r + 1] * rl);
    pk.y = cvtpk(o0[4 * r + 2] * rl, o0[4 * r + 3] * rl);
    *(uint2*)(base + 8 * r + 4 * h) = pk;
    uint2 pk2;
    pk2.x = cvtpk(o1[4 * r + 0] * rl, o1[4 * r + 1] * rl);
    pk2.y = cvtpk(o1[4 * r + 2] * rl, o1[4 * r + 3] * rl);
    *(uint2*)(base + 32 + 8 * r + 4 * h) = pk2;
  }
}

extern "C" void kernel_launch(void* const* d_in, const int* in_sizes, int n_in,
                              void* d_out, int out_size, void* d_ws, size_t ws_size,
                              hipStream_t stream) {
  (void)in_sizes; (void)n_in; (void)out_size; (void)ws_size;
  const float* xq = (const float*)d_in[0];
  const float* xk = (const float*)d_in[1];
  const float* xv = (const float*)d_in[2];
  const float* Wq = (const float*)d_in[4];
  const float* bq = (const float*)d_in[5];
  const float* Wk = (const float*)d_in[6];
  const float* bk = (const float*)d_in[7];
  const float* Wv = (const float*)d_in[8];
  const float* bv = (const float*)d_in[9];
  const float* Wo = (const float*)d_in[10];
  const float* bo = (const float*)d_in[11];

  char* ws = (char*)d_ws;
  u16* XQ  = (u16*)(ws);                       // 8MB, dead after QKV gemm
  u16* XK  = (u16*)(ws + ((size_t)8 << 20));   // 8MB, dead after QKV gemm
  u16* XV  = (u16*)(ws + ((size_t)16 << 20));  // 8MB
  u16* WTQ = (u16*)(ws + ((size_t)24 << 20));  // 2MB each
  u16* WTK = (u16*)(ws + ((size_t)26 << 20));
  u16* WTV = (u16*)(ws + ((size_t)28 << 20));
  u16* WTO = (u16*)(ws + ((size_t)30 << 20));
  u16* Qb  = (u16*)(ws + ((size_t)32 << 20));  // 8MB (32,2048,64) bf16
  u16* Kb  = (u16*)(ws + ((size_t)40 << 20));  // contiguous after Qb (rope does both)
  u16* Vb  = (u16*)(ws + ((size_t)48 << 20));
  u16* VT  = (u16*)(ws + ((size_t)8 << 20));   // aliases XK (dead) - (32,64,2048) bf16
  u16* CTX = (u16*)(ws);                       // aliases XQ (dead)

  dim3 cx(2048, 3);
  k_conv_x3<<<cx, 256, 0, stream>>>(xq, xk, xv, XQ, XK, XV);
  dim3 wt(16, 16, 4);
  k_conv_wt4<<<wt, 256, 0, stream>>>(Wq, Wk, Wv, Wo, WTQ, WTK, WTV, WTO);
  dim3 gq(32, 8, 3);
  k_gemm_qkv<<<gq, 256, 0, stream>>>(XQ, XK, XV, WTQ, WTK, WTV, bq, bk, bv, Qb, Kb, Vb);
  k_rope<<<16384, 256, 0, stream>>>((u32*)Qb);  // Q and K in one contiguous region
  dim3 vtg(32, 32);
  k_vtrans<<<vtg, 256, 0, stream>>>(Vb, VT);
  k_attn<<<2048, 64, 0, stream>>>(Qb, Kb, VT, CTX);
  dim3 gg(32, 8);
  k_gemm<1><<<gg, 256, 0, stream>>>(CTX, WTO, bo, d_out);
}

// Round 5
// 157.620 us; speedup vs baseline: 1.6051x; 1.0830x over previous
//
#include <hip/hip_runtime.h>

typedef unsigned short u16;
typedef unsigned int u32;
typedef __attribute__((ext_vector_type(8))) short short8;
typedef __attribute__((ext_vector_type(4))) float f32x4;
typedef __attribute__((ext_vector_type(16))) float f32x16;

#define DEV static __device__ __forceinline__

DEV u16 f2bf(float x) {
  union { float f; u32 u; } v; v.f = x;
  u32 r = v.u + 0x7fffu + ((v.u >> 16) & 1u);
  return (u16)(r >> 16);
}
DEV float bf2f(u16 x) {
  union { u32 u; float f; } v; v.u = ((u32)x) << 16;
  return v.f;
}
DEV u32 cvtpk(float lo, float hi) {  // D.lo=bf16(lo), D.hi=bf16(hi), RNE
  u32 r;
  asm("v_cvt_pk_bf16_f32 %0, %1, %2" : "=v"(r) : "v"(lo), "v"(hi));
  return r;
}
DEV void swap32(u32& a, u32& b) {  // a' = [a.lo32 | b.lo32], b' = [a.hi32 | b.hi32]
  asm("v_permlane32_swap_b32 %0, %1" : "+v"(a), "+v"(b));
}

DEV void gload_lds16(const void* g, void* l) {
  __builtin_amdgcn_global_load_lds(
      (__attribute__((address_space(1))) u32*)((void*)g),
      (__attribute__((address_space(3))) u32*)l, 16, 0, 0);
}

DEV void mfma_bf16(f32x4& d, short8 a, short8 b) {
  asm("v_mfma_f32_16x16x32_bf16 %0, %1, %2, %0" : "+v"(d) : "v"(a), "v"(b));
}
DEV void mfma32(f32x16& d, short8 a, short8 b) {
  asm("v_mfma_f32_32x32x16_bf16 %0, %1, %2, %0" : "+v"(d) : "v"(a), "v"(b));
}

// ---------------- fp32 -> bf16 cast for q/k/v inputs, fused over grid.y ----------------
__global__ __launch_bounds__(256) void k_conv_x3(const float* __restrict__ x0, const float* __restrict__ x1,
                                                 const float* __restrict__ x2, u16* __restrict__ o0,
                                                 u16* __restrict__ o1, u16* __restrict__ o2) {
  int z = blockIdx.y;
  const float* in = (z == 0) ? x0 : (z == 1) ? x1 : x2;
  u16* out = (z == 0) ? o0 : (z == 1) ? o1 : o2;
  int i = blockIdx.x * 256 + threadIdx.x;
  const float4* p = (const float4*)in;
  float4 a = p[i * 2], b = p[i * 2 + 1];
  uint4 o;
  o.x = cvtpk(a.x, a.y); o.y = cvtpk(a.z, a.w);
  o.z = cvtpk(b.x, b.y); o.w = cvtpk(b.z, b.w);
  ((uint4*)out)[i] = o;
}

// ---------------- W[k][n] fp32 -> Wt[n][k] bf16, 64x64 tiles, fused over grid.z ----------------
__global__ __launch_bounds__(256) void k_conv_wt4(const float* __restrict__ W0, const float* __restrict__ W1,
                                                  const float* __restrict__ W2, const float* __restrict__ W3,
                                                  u16* __restrict__ T0, u16* __restrict__ T1,
                                                  u16* __restrict__ T2, u16* __restrict__ T3) {
  int z = blockIdx.z;
  const float* W = (z == 0) ? W0 : (z == 1) ? W1 : (z == 2) ? W2 : W3;
  u16* Wt = (z == 0) ? T0 : (z == 1) ? T1 : (z == 2) ? T2 : T3;
  __shared__ u16 tile[64][65];
  int t = threadIdx.x;
  int k0 = blockIdx.x * 64, n0 = blockIdx.y * 64;
  int rr = t >> 4, cc = (t & 15) * 4;
#pragma unroll
  for (int i = 0; i < 4; ++i) {
    int r = rr + i * 16;
    float4 v = *(const float4*)&W[(size_t)(k0 + r) * 1024 + n0 + cc];
    tile[r][cc + 0] = f2bf(v.x); tile[r][cc + 1] = f2bf(v.y);
    tile[r][cc + 2] = f2bf(v.z); tile[r][cc + 3] = f2bf(v.w);
  }
  __syncthreads();
#pragma unroll
  for (int i = 0; i < 4; ++i) {
    int n = rr + i * 16;
    u16 a0 = tile[cc + 0][n], a1 = tile[cc + 1][n], a2 = tile[cc + 2][n], a3 = tile[cc + 3][n];
    uint2 pk;
    pk.x = (u32)a0 | ((u32)a1 << 16);
    pk.y = (u32)a2 | ((u32)a3 << 16);
    *(uint2*)&Wt[(size_t)(n0 + n) * 1024 + k0 + cc] = pk;
  }
}

// ---------------- V (b,h,s,d) bf16 -> Vt (b,h,d,s) bf16, 64x64 tiles ----------------
__global__ __launch_bounds__(256) void k_vtrans(const u16* __restrict__ in, u16* __restrict__ out) {
  __shared__ u16 tile[64][65];
  int t = threadIdx.x;
  int s0 = blockIdx.x * 64;
  size_t base = (size_t)blockIdx.y * 131072;
#pragma unroll
  for (int p = 0; p < 2; ++p) {
    int i = p * 256 + t;
    int r = i >> 3, c = i & 7;
    short8 v = *(const short8*)(in + base + (size_t)(s0 + r) * 64 + c * 8);
#pragma unroll
    for (int j = 0; j < 8; ++j) tile[r][c * 8 + j] = (u16)(unsigned short)v[j];
  }
  __syncthreads();
#pragma unroll
  for (int p = 0; p < 2; ++p) {
    int i = p * 256 + t;
    int d = i >> 3, c = i & 7;
    short8 o;
#pragma unroll
    for (int j = 0; j < 8; ++j) o[j] = (short)tile[c * 8 + j][d];
    *(short8*)(out + base + (size_t)d * 2048 + s0 + c * 8) = o;
  }
}

// ---------------- GEMM core, BK=64, XOR-swizzled LDS (2-way conflict = free) ----------------
#define GEMM_BODY(A_, Bt_)                                                                       \
  __shared__ __align__(16) char sA[16384];                                                       \
  __shared__ __align__(16) char sB[16384];                                                       \
  int tid = threadIdx.x, lane = tid & 63, w = tid >> 6;                                          \
  int l15 = lane & 15, lg = lane >> 4;                                                           \
  int bm = blockIdx.x * 128, bn = blockIdx.y * 128;                                              \
  int wm = (w >> 1) * 64, wn = (w & 1) * 64;                                                     \
  f32x4 acc[4][4];                                                                               \
  _Pragma("unroll") for (int i = 0; i < 4; ++i)                                                  \
      _Pragma("unroll") for (int j = 0; j < 4; ++j) acc[i][j] = (f32x4){0.f, 0.f, 0.f, 0.f};     \
  for (int kt = 0; kt < 16; ++kt) {                                                              \
    _Pragma("unroll") for (int p = 0; p < 4; ++p) {                                              \
      int idx = p * 256 + tid;                                                                   \
      int row = idx >> 3;                                                                        \
      int c8 = (idx & 7) ^ (row & 7);                                                            \
      gload_lds16(A_ + (size_t)(bm + row) * 1024 + kt * 64 + c8 * 8, sA + p * 4096 + w * 1024);  \
      gload_lds16(Bt_ + (size_t)(bn + row) * 1024 + kt * 64 + c8 * 8, sB + p * 4096 + w * 1024); \
    }                                                                                            \
    __syncthreads();                                                                             \
    short8 af[4][2], bf[4][2];                                                                   \
    _Pragma("unroll") for (int i = 0; i < 4; ++i) _Pragma("unroll") for (int s = 0; s < 2; ++s) { \
      int cs = ((s * 4 + lg) ^ (l15 & 7)) * 16;                                                  \
      af[i][s] = *(const short8*)(sA + (wm + i * 16 + l15) * 128 + cs);                          \
      bf[i][s] = *(const short8*)(sB + (wn + i * 16 + l15) * 128 + cs);                          \
    }                                                                                            \
    _Pragma("unroll") for (int s = 0; s < 2; ++s)                                                \
        _Pragma("unroll") for (int i = 0; i < 4; ++i)                                            \
            _Pragma("unroll") for (int j = 0; j < 4; ++j) mfma_bf16(acc[i][j], af[i][s], bf[j][s]); \
    __syncthreads();                                                                             \
  }

// MODE 0: write bf16 to (b,h,s,d) head-split layout.  MODE 1: write fp32 row-major.
template <int MODE>
__global__ __launch_bounds__(256) void k_gemm(const u16* __restrict__ A, const u16* __restrict__ Bt,
                                              const float* __restrict__ bias, void* __restrict__ dst) {
  GEMM_BODY(A, Bt)
  float bv[4];
#pragma unroll
  for (int j = 0; j < 4; ++j) bv[j] = bias[bn + wn + j * 16 + l15];
#pragma unroll
  for (int i = 0; i < 4; ++i) {
#pragma unroll
    for (int j = 0; j < 4; ++j) {
#pragma unroll
      for (int r = 0; r < 4; ++r) {
        int m = bm + wm + i * 16 + lg * 4 + r;
        int n = bn + wn + j * 16 + l15;
        float v = acc[i][j][r] + bv[j];
        if (MODE == 0) {
          int bb = m >> 11, s = m & 2047, h = n >> 6, d = n & 63;
          ((u16*)dst)[(((size_t)(bb * 16 + h)) * 2048 + s) * 64 + d] = f2bf(v);
        } else {
          ((float*)dst)[(size_t)m * 1024 + n] = v;
        }
      }
    }
  }
}

// QKV fused over blockIdx.z
__global__ __launch_bounds__(256) void k_gemm_qkv(const u16* __restrict__ Aq, const u16* __restrict__ Ak,
                                                  const u16* __restrict__ Av, const u16* __restrict__ Wq,
                                                  const u16* __restrict__ Wk, const u16* __restrict__ Wv,
                                                  const float* __restrict__ bq, const float* __restrict__ bk,
                                                  const float* __restrict__ bv, u16* __restrict__ Qo,
                                                  u16* __restrict__ Ko, u16* __restrict__ Vo) {
  int z = blockIdx.z;
  const u16* A = (z == 0) ? Aq : (z == 1) ? Ak : Av;
  const u16* Bt = (z == 0) ? Wq : (z == 1) ? Wk : Wv;
  const float* bias = (z == 0) ? bq : (z == 1) ? bk : bv;
  u16* dst = (z == 0) ? Qo : (z == 1) ? Ko : Vo;
  GEMM_BODY(A, Bt)
  float bvv[4];
#pragma unroll
  for (int j = 0; j < 4; ++j) bvv[j] = bias[bn + wn + j * 16 + l15];
#pragma unroll
  for (int i = 0; i < 4; ++i) {
#pragma unroll
    for (int j = 0; j < 4; ++j) {
#pragma unroll
      for (int r = 0; r < 4; ++r) {
        int m = bm + wm + i * 16 + lg * 4 + r;
        int n = bn + wn + j * 16 + l15;
        float v = acc[i][j][r] + bvv[j];
        int bb = m >> 11, s = m & 2047, h = n >> 6, d = n & 63;
        dst[(((size_t)(bb * 16 + h)) * 2048 + s) * 64 + d] = f2bf(v);
      }
    }
  }
}

// ---------------- RoPE in-place, Q and K in one contiguous 16MB region ----------------
__global__ __launch_bounds__(256) void k_rope(u32* __restrict__ buf) {
  int p = blockIdx.x * 256 + threadIdx.x;  // 4M pairs (Q then K)
  u32 u = buf[p];
  float xe = bf2f((u16)(u & 0xffffu));
  float xo = bf2f((u16)(u >> 16));
  int dp = p & 31;
  int s = (p >> 5) & 2047;
  float theta = exp2f((float)dp * (-2.0f / 64.0f) * 13.287712379549449f);  // 10000^(-2i/64)
  float ang = (float)s * theta;
  float sn, cs;
  sincosf(ang, &sn, &cs);
  float re = xe * cs - xo * sn;
  float ro = xe * sn + xo * cs;
  buf[p] = (u32)f2bf(re) | ((u32)f2bf(ro) << 16);
}

// ---------------- causal flash attention, 32x32 MFMA, split-KV x4 ----------------
// grid 2048 blocks x 256 thr (4 waves). Block owns one 32-row q-tile of one bh.
// Wave w processes kv-tiles t%4==w independently (no barriers in loop -> compiler
// pipelines; waves hide each other's latency). LDS tree-merge of (m,l,O) at end.
__global__ __launch_bounds__(256, 4) void k_attn(const u16* __restrict__ Q, const u16* __restrict__ K,
                                                 const u16* __restrict__ Vt, u16* __restrict__ ctx) {
  __shared__ float sM[2][64], sL[2][64];
  __shared__ float sO[2][32][64];  // [slot][reg][lane] - lane-contiguous, 2-way = free
  const float KL2E = 0.18033688011112042f;  // (1/8) * log2(e)
  int id = blockIdx.x;
  int bh = ((id >> 3) & 3) * 8 + (id & 7);  // XCD-cluster: bh%8 == id%8
  int qt = 63 - (id >> 5);                  // heavy q-tiles first
  int tid = threadIdx.x;
  int w = tid >> 6, lane = tid & 63;
  int q31 = lane & 31, h = lane >> 5;
  const u16* Qg = Q + (size_t)bh * 131072;
  const u16* Kg = K + (size_t)bh * 131072;
  const u16* Vg = Vt + (size_t)bh * 131072;
  int qrow = qt * 32 + q31;

  short8 qf[4];
#pragma unroll
  for (int m = 0; m < 4; ++m)
    qf[m] = *(const short8*)(Qg + (size_t)qrow * 64 + m * 16 + h * 8);

  f32x16 o0, o1;
#pragma unroll
  for (int r = 0; r < 16; ++r) { o0[r] = 0.f; o1[r] = 0.f; }
  float mrun = -3e38f, lrun = 0.f;
  int ntile = (qt >> 1) + 1;

  for (int t = w; t < ntile; t += 4) {
    int kv = t << 6;
    // K fragments: A[row=key(lane&31)][k = d-slice m*16+h*8..+7]
    short8 kf0[4], kf1[4];
#pragma unroll
    for (int m = 0; m < 4; ++m) {
      kf0[m] = *(const short8*)(Kg + (size_t)(kv + q31) * 64 + m * 16 + h * 8);
      kf1[m] = *(const short8*)(Kg + (size_t)(kv + 32 + q31) * 64 + m * 16 + h * 8);
    }
    f32x16 pA, pB;
#pragma unroll
    for (int r = 0; r < 16; ++r) { pA[r] = 0.f; pB[r] = 0.f; }
#pragma unroll
    for (int m = 0; m < 4; ++m) mfma32(pA, kf0[m], qf[m]);
#pragma unroll
    for (int m = 0; m < 4; ++m) mfma32(pB, kf1[m], qf[m]);

    if (t == ntile - 1) {  // diagonal tile: mask key > q
#pragma unroll
      for (int r = 0; r < 16; ++r) {
        int keyA = kv + (r & 3) + 8 * (r >> 2) + 4 * h;
        if (keyA > qrow) pA[r] = -1e9f;
        if (keyA + 32 > qrow) pB[r] = -1e9f;
      }
    }
    // online softmax: lane owns q-row q31 (16 keys here, other 16 in lane^32)
    float pm = pA[0];
#pragma unroll
    for (int r = 1; r < 16; ++r) pm = fmaxf(pm, pA[r]);
#pragma unroll
    for (int r = 0; r < 16; ++r) pm = fmaxf(pm, pB[r]);
    pm = fmaxf(pm, __shfl_xor(pm, 32));
    float mnew = fmaxf(mrun, pm);
    int upd = pm > mrun;
    float alpha = exp2f((mrun - mnew) * KL2E);
    mrun = mnew;
    float ps = 0.f;
#pragma unroll
    for (int r = 0; r < 16; ++r) {
      pA[r] = exp2f((pA[r] - mnew) * KL2E);
      ps += pA[r];
    }
#pragma unroll
    for (int r = 0; r < 16; ++r) {
      pB[r] = exp2f((pB[r] - mnew) * KL2E);
      ps += pB[r];
    }
    ps += __shfl_xor(ps, 32);
    lrun = lrun * alpha + ps;
    if (__any(upd)) {
#pragma unroll
      for (int r = 0; r < 16; ++r) { o0[r] *= alpha; o1[r] *= alpha; }
    }
    // V^T fragments: A[row=d(lane&31)][k = key m*16+h*8..+7]
    short8 vf0[4], vf1[4];
#pragma unroll
    for (int m = 0; m < 4; ++m) {
      vf0[m] = *(const short8*)(Vg + (size_t)q31 * 2048 + kv + m * 16 + h * 8);
      vf1[m] = *(const short8*)(Vg + (size_t)(32 + q31) * 2048 + kv + m * 16 + h * 8);
    }
    // P -> bf16 B-frags via cvt_pk + permlane32_swap; PV accumulate
#pragma unroll
    for (int m = 0; m < 4; ++m) {
      int mlow = 8 * (m & 1);
      u32 u0, u1, v0, v1;
      if (m < 2) {
        u0 = cvtpk(pA[mlow + 0], pA[mlow + 1]);
        u1 = cvtpk(pA[mlow + 2], pA[mlow + 3]);
        v0 = cvtpk(pA[mlow + 4], pA[mlow + 5]);
        v1 = cvtpk(pA[mlow + 6], pA[mlow + 7]);
      } else {
        u0 = cvtpk(pB[mlow + 0], pB[mlow + 1]);
        u1 = cvtpk(pB[mlow + 2], pB[mlow + 3]);
        v0 = cvtpk(pB[mlow + 4], pB[mlow + 5]);
        v1 = cvtpk(pB[mlow + 6], pB[mlow + 7]);
      }
      swap32(u0, v0);
      swap32(u1, v1);
      union { u32 wd[4]; short8 s; } pf;
      pf.wd[0] = u0; pf.wd[1] = u1; pf.wd[2] = v0; pf.wd[3] = v1;
      mfma32(o0, vf0[m], pf.s);
      mfma32(o1, vf1[m], pf.s);
    }
  }

  // ---- LDS tree merge of 4 per-wave partials (elementwise per lane) ----
#define STOREW(S)                                        \
  {                                                      \
    sM[S][lane] = mrun; sL[S][lane] = lrun;              \
    _Pragma("unroll") for (int r = 0; r < 16; ++r) {     \
      sO[S][r][lane] = o0[r];                            \
      sO[S][16 + r][lane] = o1[r];                       \
    }                                                    \
  }
#define MERGEW(S)                                                      \
  {                                                                    \
    float m2 = sM[S][lane], l2 = sL[S][lane];                          \
    float mn = fmaxf(mrun, m2);                                        \
    float a = exp2f((mrun - mn) * KL2E);                               \
    float b = exp2f((m2 - mn) * KL2E);                                 \
    lrun = lrun * a + l2 * b;                                          \
    _Pragma("unroll") for (int r = 0; r < 16; ++r) {                   \
      o0[r] = o0[r] * a + sO[S][r][lane] * b;                          \
      o1[r] = o1[r] * a + sO[S][16 + r][lane] * b;                     \
    }                                                                  \
    mrun = mn;                                                         \
  }

  if (w == 1) STOREW(0);
  if (w == 3) STOREW(1);
  __syncthreads();
  if (w == 0) MERGEW(0);
  if (w == 2) MERGEW(1);
  __syncthreads();
  if (w == 2) STOREW(0);
  __syncthreads();
  if (w == 0) {
    MERGEW(0);
    float rl = 1.f / lrun;
    int bb = bh >> 4, hh = bh & 15;
    u16* base = ctx + ((size_t)(bb * 2048 + qrow)) * 1024 + hh * 64;
#pragma unroll
    for (int r = 0; r < 4; ++r) {
      uint2 pk;
      pk.x = cvtpk(o0[4 * r + 0] * rl, o0[4 * r + 1] * rl);
      pk.y = cvtpk(o0[4 * r + 2] * rl, o0[4 * r + 3] * rl);
      *(uint2*)(base + 8 * r + 4 * h) = pk;
      uint2 pk2;
      pk2.x = cvtpk(o1[4 * r + 0] * rl, o1[4 * r + 1] * rl);
      pk2.y = cvtpk(o1[4 * r + 2] * rl, o1[4 * r + 3] * rl);
      *(uint2*)(base + 32 + 8 * r + 4 * h) = pk2;
    }
  }
#undef STOREW
#undef MERGEW
}

extern "C" void kernel_launch(void* const* d_in, const int* in_sizes, int n_in,
                              void* d_out, int out_size, void* d_ws, size_t ws_size,
                              hipStream_t stream) {
  (void)in_sizes; (void)n_in; (void)out_size; (void)ws_size;
  const float* xq = (const float*)d_in[0];
  const float* xk = (const float*)d_in[1];
  const float* xv = (const float*)d_in[2];
  const float* Wq = (const float*)d_in[4];
  const float* bq = (const float*)d_in[5];
  const float* Wk = (const float*)d_in[6];
  const float* bk = (const float*)d_in[7];
  const float* Wv = (const float*)d_in[8];
  const float* bv = (const float*)d_in[9];
  const float* Wo = (const float*)d_in[10];
  const float* bo = (const float*)d_in[11];

  char* ws = (char*)d_ws;
  u16* XQ  = (u16*)(ws);                       // 8MB, dead after QKV gemm
  u16* XK  = (u16*)(ws + ((size_t)8 << 20));   // 8MB, dead after QKV gemm
  u16* XV  = (u16*)(ws + ((size_t)16 << 20));  // 8MB
  u16* WTQ = (u16*)(ws + ((size_t)24 << 20));  // 2MB each
  u16* WTK = (u16*)(ws + ((size_t)26 << 20));
  u16* WTV = (u16*)(ws + ((size_t)28 << 20));
  u16* WTO = (u16*)(ws + ((size_t)30 << 20));
  u16* Qb  = (u16*)(ws + ((size_t)32 << 20));  // 8MB (32,2048,64) bf16
  u16* Kb  = (u16*)(ws + ((size_t)40 << 20));  // contiguous after Qb (rope does both)
  u16* Vb  = (u16*)(ws + ((size_t)48 << 20));
  u16* VT  = (u16*)(ws + ((size_t)8 << 20));   // aliases XK (dead) - (32,64,2048) bf16
  u16* CTX = (u16*)(ws);                       // aliases XQ (dead)

  dim3 cx(2048, 3);
  k_conv_x3<<<cx, 256, 0, stream>>>(xq, xk, xv, XQ, XK, XV);
  dim3 wt(16, 16, 4);
  k_conv_wt4<<<wt, 256, 0, stream>>>(Wq, Wk, Wv, Wo, WTQ, WTK, WTV, WTO);
  dim3 gq(32, 8, 3);
  k_gemm_qkv<<<gq, 256, 0, stream>>>(XQ, XK, XV, WTQ, WTK, WTV, bq, bk, bv, Qb, Kb, Vb);
  k_rope<<<16384, 256, 0, stream>>>((u32*)Qb);  // Q and K in one contiguous region
  dim3 vtg(32, 32);
  k_vtrans<<<vtg, 256, 0, stream>>>(Vb, VT);
  k_attn<<<2048, 256, 0, stream>>>(Qb, Kb, VT, CTX);
  dim3 gg(32, 8);
  k_gemm<1><<<gg, 256, 0, stream>>>(CTX, WTO, bo, d_out);
}